// Round 3
// baseline (466.709 us; speedup 1.0000x reference)
//
#include <hip/hip_runtime.h>

#define N_NODESC 50000
#define N_EDGESC 800000
#define NFEATC 128
#define NHIDC 64
#define NHEADC 4
#define NBASEC 8
#define NCLASSC 40
#define HD1C (NHEADC * NHIDC)        // 256

__device__ inline float bf2f(unsigned short u) {
  union { unsigned int i; float f; } v;
  v.i = ((unsigned int)u) << 16;
  return v.f;
}
__device__ inline unsigned short f2bf(float x) {
  union { float f; unsigned int i; } v;
  v.f = x;
  unsigned int r = v.i + 0x7FFF + ((v.i >> 16) & 1);  // RNE
  return (unsigned short)(r >> 16);
}

// ---------------- fp32 GEMM, 128x128 tile, 8x8/thread, bf16 output ----------------
__global__ __launch_bounds__(256) void gemm128_bf16(const float* __restrict__ A,
                                                    const float* __restrict__ B,
                                                    unsigned short* __restrict__ Cb,
                                                    int M, int N, int K) {
  __shared__ float As[16][132];
  __shared__ float Bs[16][132];
  const int tid = threadIdx.x;
  const int tx = tid & 15;         // col group
  const int ty = tid >> 4;         // row group
  const int row0 = blockIdx.x * 128;
  const int col0 = blockIdx.y * 128;
  float acc[8][8] = {{0.f}};

  for (int k0 = 0; k0 < K; k0 += 16) {
    // A tile: 128 rows x 16 k. thread -> kk = tid&15, r = tid>>4, 8 passes of 16 rows
    {
      const int kk = tid & 15;
      const int r = tid >> 4;
#pragma unroll
      for (int p = 0; p < 8; ++p) {
        const int row = row0 + r + p * 16;
        float v = 0.f;
        if (row < M) v = A[(size_t)row * K + k0 + kk];
        As[kk][r + p * 16] = v;
      }
    }
    // B tile: 16 k x 128 cols. thread -> c = tid&127, kk0 = tid>>7, 8 passes
    {
      const int c = tid & 127;
      const int kk0 = tid >> 7;
#pragma unroll
      for (int p = 0; p < 8; ++p) {
        const int kk = kk0 + p * 2;
        const int col = col0 + c;
        float v = 0.f;
        if (col < N) v = B[(size_t)(k0 + kk) * N + col];
        Bs[kk][c] = v;
      }
    }
    __syncthreads();
#pragma unroll
    for (int kk = 0; kk < 16; ++kk) {
      float av[8], bv[8];
      *reinterpret_cast<float4*>(&av[0]) = *reinterpret_cast<const float4*>(&As[kk][ty * 8]);
      *reinterpret_cast<float4*>(&av[4]) = *reinterpret_cast<const float4*>(&As[kk][ty * 8 + 4]);
      *reinterpret_cast<float4*>(&bv[0]) = *reinterpret_cast<const float4*>(&Bs[kk][tx * 8]);
      *reinterpret_cast<float4*>(&bv[4]) = *reinterpret_cast<const float4*>(&Bs[kk][tx * 8 + 4]);
#pragma unroll
      for (int i = 0; i < 8; ++i)
#pragma unroll
        for (int j = 0; j < 8; ++j) acc[i][j] += av[i] * bv[j];
    }
    __syncthreads();
  }
#pragma unroll
  for (int i = 0; i < 8; ++i) {
    const int row = row0 + ty * 8 + i;
    if (row >= M) continue;
#pragma unroll
    for (int j = 0; j < 8; ++j) {
      const int col = col0 + tx * 8 + j;
      if (col < N) Cb[(size_t)row * N + col] = f2bf(acc[i][j]);
    }
  }
}

// ---------------- fp32 GEMM, 64x64 tile, 4x4/thread, fp32 and/or bf16 out ----------------
__global__ __launch_bounds__(256) void gemm64(const float* __restrict__ A,
                                              const float* __restrict__ B,
                                              float* __restrict__ Cf,
                                              unsigned short* __restrict__ Cb,
                                              int M, int N, int K) {
  __shared__ float As[16][68];
  __shared__ float Bs[16][68];
  const int tid = threadIdx.x;
  const int tx = tid & 15;
  const int ty = tid >> 4;
  const int row0 = blockIdx.x * 64;
  const int col0 = blockIdx.y * 64;
  float acc[4][4] = {{0.f}};

  for (int k0 = 0; k0 < K; k0 += 16) {
    {
      const int kk = tid & 15;
      const int r = tid >> 4;
#pragma unroll
      for (int p = 0; p < 4; ++p) {
        const int row = row0 + r + p * 16;
        float v = 0.f;
        if (row < M) v = A[(size_t)row * K + k0 + kk];
        As[kk][r + p * 16] = v;
      }
    }
    {
      const int c = tid & 63;
      const int kk0 = tid >> 6;
#pragma unroll
      for (int p = 0; p < 4; ++p) {
        const int kk = kk0 + p * 4;
        const int col = col0 + c;
        float v = 0.f;
        if (col < N) v = B[(size_t)(k0 + kk) * N + col];
        Bs[kk][c] = v;
      }
    }
    __syncthreads();
#pragma unroll
    for (int kk = 0; kk < 16; ++kk) {
      const float4 av = *reinterpret_cast<const float4*>(&As[kk][ty * 4]);
      const float4 bv = *reinterpret_cast<const float4*>(&Bs[kk][tx * 4]);
      acc[0][0] += av.x * bv.x; acc[0][1] += av.x * bv.y; acc[0][2] += av.x * bv.z; acc[0][3] += av.x * bv.w;
      acc[1][0] += av.y * bv.x; acc[1][1] += av.y * bv.y; acc[1][2] += av.y * bv.z; acc[1][3] += av.y * bv.w;
      acc[2][0] += av.z * bv.x; acc[2][1] += av.z * bv.y; acc[2][2] += av.z * bv.z; acc[2][3] += av.z * bv.w;
      acc[3][0] += av.w * bv.x; acc[3][1] += av.w * bv.y; acc[3][2] += av.w * bv.z; acc[3][3] += av.w * bv.w;
    }
    __syncthreads();
  }
#pragma unroll
  for (int i = 0; i < 4; ++i) {
    const int row = row0 + ty * 4 + i;
    if (row >= M) continue;
#pragma unroll
    for (int j = 0; j < 4; ++j) {
      const int col = col0 + tx * 4 + j;
      if (col < N) {
        if (Cf) Cf[(size_t)row * N + col] = acc[i][j];
        if (Cb) Cb[(size_t)row * N + col] = f2bf(acc[i][j]);
      }
    }
  }
}

// ---------------- per-node attention scalars ----------------
__global__ void attn_scalars1(const float* __restrict__ s1,
                              const float* __restrict__ cs1, const float* __restrict__ cd1,
                              float* __restrict__ esrc, float* __restrict__ edst) {
  const int n = blockIdx.x * blockDim.x + threadIdx.x;
  if (n >= N_NODESC) return;
  const float* s = s1 + (size_t)n * NBASEC;
  float sb[NBASEC];
#pragma unroll
  for (int b = 0; b < NBASEC; ++b) sb[b] = s[b];
#pragma unroll
  for (int h = 0; h < NHEADC; ++h) {
    float a = 0.f, d = 0.f;
#pragma unroll
    for (int b = 0; b < NBASEC; ++b) {
      a += sb[b] * cs1[b * NHEADC + h];
      d += sb[b] * cd1[b * NHEADC + h];
    }
    esrc[n * NHEADC + h] = a;
    edst[n * NHEADC + h] = d;
  }
}

__global__ void attn_scalars2(const float* __restrict__ s2,
                              const float* __restrict__ cs2, const float* __restrict__ cd2,
                              float* __restrict__ esrc, float* __restrict__ edst) {
  const int n = blockIdx.x * blockDim.x + threadIdx.x;
  if (n >= N_NODESC) return;
  const float* s = s2 + (size_t)n * NBASEC;
  float a = 0.f, d = 0.f;
#pragma unroll
  for (int b = 0; b < NBASEC; ++b) {
    a += s[b] * cs2[b];
    d += s[b] * cd2[b];
  }
  esrc[n] = a;
  edst[n] = d;
}

// ---------------- CSR build (by destination node) ----------------
__global__ void hist_kernel(const int* __restrict__ dst, int* __restrict__ counts) {
  const int e = blockIdx.x * blockDim.x + threadIdx.x;
  if (e < N_EDGESC) atomicAdd(&counts[dst[e]], 1);
}

#define SCAN_NB ((N_NODESC + 255) / 256)   // 196

__global__ void reduce_counts(const int* __restrict__ counts, int* __restrict__ bsums) {
  __shared__ int sm[256];
  const int i = blockIdx.x * 256 + threadIdx.x;
  sm[threadIdx.x] = (i < N_NODESC) ? counts[i] : 0;
  __syncthreads();
  for (int d = 128; d > 0; d >>= 1) {
    if (threadIdx.x < (unsigned)d) sm[threadIdx.x] += sm[threadIdx.x + d];
    __syncthreads();
  }
  if (threadIdx.x == 0) bsums[blockIdx.x] = sm[0];
}

__global__ void scan_bsums_k(int* __restrict__ bsums) {
  __shared__ int sm[256];
  const int v = (threadIdx.x < SCAN_NB) ? bsums[threadIdx.x] : 0;
  sm[threadIdx.x] = v;
  __syncthreads();
  for (int d = 1; d < 256; d <<= 1) {
    const int t = (threadIdx.x >= (unsigned)d) ? sm[threadIdx.x - d] : 0;
    __syncthreads();
    sm[threadIdx.x] += t;
    __syncthreads();
  }
  if (threadIdx.x < SCAN_NB) bsums[threadIdx.x] = sm[threadIdx.x] - v;  // exclusive
}

__global__ void scan_final(const int* __restrict__ counts, const int* __restrict__ bsums,
                           int* __restrict__ offsets) {
  __shared__ int sm[256];
  const int i = blockIdx.x * 256 + threadIdx.x;
  const int v = (i < N_NODESC) ? counts[i] : 0;
  sm[threadIdx.x] = v;
  __syncthreads();
  for (int d = 1; d < 256; d <<= 1) {
    const int t = (threadIdx.x >= (unsigned)d) ? sm[threadIdx.x - d] : 0;
    __syncthreads();
    sm[threadIdx.x] += t;
    __syncthreads();
  }
  if (i < N_NODESC) offsets[i] = bsums[blockIdx.x] + sm[threadIdx.x] - v;
  if (i == 0) offsets[N_NODESC] = N_EDGESC;
}

__global__ void scatter_kernel(const int* __restrict__ dst, const int* __restrict__ src,
                               const int* __restrict__ offsets, int* __restrict__ counts,
                               int* __restrict__ srcs_csr) {
  const int e = blockIdx.x * blockDim.x + threadIdx.x;
  if (e >= N_EDGESC) return;
  const int n = dst[e];
  const int pos = offsets[n] + atomicSub(&counts[n], 1) - 1;
  srcs_csr[pos] = src[e];
}

// ---------------- layer-1 single-pass softmax-aggregate + bias + ELU ----------------
__global__ __launch_bounds__(256) void agg1_kernel(
    const unsigned short* __restrict__ h1b, const float* __restrict__ esrc,
    const float* __restrict__ edst, const int* __restrict__ srcs,
    const int* __restrict__ offsets, const float* __restrict__ bias,
    float* __restrict__ hact) {
  const int wv = threadIdx.x >> 6;
  const int lane = threadIdx.x & 63;
  const int n = blockIdx.x * 4 + wv;
  if (n >= N_NODESC) return;
  const int h = lane >> 4;
  const int f = lane << 2;
  const int beg = offsets[n], end = offsets[n + 1];
  const float ed = edst[n * NHEADC + h];

  float wsum = 0.f;
  float ax = 0.f, ay = 0.f, az = 0.f, aw = 0.f;
  int i = beg;
  for (; i + 4 <= end; i += 4) {
    const int s0 = srcs[i], s1 = srcs[i + 1], s2 = srcs[i + 2], s3 = srcs[i + 3];
    float t0 = esrc[s0 * NHEADC + h] + ed;
    float t1 = esrc[s1 * NHEADC + h] + ed;
    float t2 = esrc[s2 * NHEADC + h] + ed;
    float t3 = esrc[s3 * NHEADC + h] + ed;
    const ushort4 h0 = *reinterpret_cast<const ushort4*>(h1b + (size_t)s0 * HD1C + f);
    const ushort4 h1 = *reinterpret_cast<const ushort4*>(h1b + (size_t)s1 * HD1C + f);
    const ushort4 h2 = *reinterpret_cast<const ushort4*>(h1b + (size_t)s2 * HD1C + f);
    const ushort4 h3 = *reinterpret_cast<const ushort4*>(h1b + (size_t)s3 * HD1C + f);
    t0 = t0 > 0.f ? t0 : 0.2f * t0;
    t1 = t1 > 0.f ? t1 : 0.2f * t1;
    t2 = t2 > 0.f ? t2 : 0.2f * t2;
    t3 = t3 > 0.f ? t3 : 0.2f * t3;
    const float a0 = __expf(t0), a1 = __expf(t1), a2 = __expf(t2), a3 = __expf(t3);
    wsum += (a0 + a1) + (a2 + a3);
    ax += a0 * bf2f(h0.x) + a1 * bf2f(h1.x) + a2 * bf2f(h2.x) + a3 * bf2f(h3.x);
    ay += a0 * bf2f(h0.y) + a1 * bf2f(h1.y) + a2 * bf2f(h2.y) + a3 * bf2f(h3.y);
    az += a0 * bf2f(h0.z) + a1 * bf2f(h1.z) + a2 * bf2f(h2.z) + a3 * bf2f(h3.z);
    aw += a0 * bf2f(h0.w) + a1 * bf2f(h1.w) + a2 * bf2f(h2.w) + a3 * bf2f(h3.w);
  }
  for (; i < end; ++i) {
    const int s = srcs[i];
    float t = esrc[s * NHEADC + h] + ed;
    t = t > 0.f ? t : 0.2f * t;
    const float a = __expf(t);
    const ushort4 hv = *reinterpret_cast<const ushort4*>(h1b + (size_t)s * HD1C + f);
    wsum += a;
    ax += a * bf2f(hv.x); ay += a * bf2f(hv.y); az += a * bf2f(hv.z); aw += a * bf2f(hv.w);
  }
  const float inv = 1.f / (wsum + 1e-16f);
  const float4 bb = *reinterpret_cast<const float4*>(bias + f);
  float4 o;
  o.x = ax * inv + bb.x; o.x = o.x > 0.f ? o.x : __expf(o.x) - 1.f;
  o.y = ay * inv + bb.y; o.y = o.y > 0.f ? o.y : __expf(o.y) - 1.f;
  o.z = az * inv + bb.z; o.z = o.z > 0.f ? o.z : __expf(o.z) - 1.f;
  o.w = aw * inv + bb.w; o.w = o.w > 0.f ? o.w : __expf(o.w) - 1.f;
  *reinterpret_cast<float4*>(hact + (size_t)n * HD1C + f) = o;
}

// ---------------- layer-2 single-pass softmax-aggregate (1 head, 40 classes) ----------------
__global__ __launch_bounds__(256) void agg2_kernel(
    const unsigned short* __restrict__ g2b, const float* __restrict__ esrc,
    const float* __restrict__ edst, const int* __restrict__ srcs,
    const int* __restrict__ offsets, float* __restrict__ out) {
  const int wv = threadIdx.x >> 6;
  const int lane = threadIdx.x & 63;
  const int n = blockIdx.x * 4 + wv;
  if (n >= N_NODESC) return;
  const int beg = offsets[n], end = offsets[n + 1];
  const float ed = edst[n];

  float wsum = 0.f, acc = 0.f;
  const bool act = lane < NCLASSC;
  int i = beg;
  for (; i + 4 <= end; i += 4) {
    const int s0 = srcs[i], s1 = srcs[i + 1], s2 = srcs[i + 2], s3 = srcs[i + 3];
    float t0 = esrc[s0] + ed, t1 = esrc[s1] + ed, t2 = esrc[s2] + ed, t3 = esrc[s3] + ed;
    float g0 = 0.f, g1 = 0.f, g2v = 0.f, g3 = 0.f;
    if (act) {
      g0 = bf2f(g2b[(size_t)s0 * NCLASSC + lane]);
      g1 = bf2f(g2b[(size_t)s1 * NCLASSC + lane]);
      g2v = bf2f(g2b[(size_t)s2 * NCLASSC + lane]);
      g3 = bf2f(g2b[(size_t)s3 * NCLASSC + lane]);
    }
    t0 = t0 > 0.f ? t0 : 0.2f * t0;
    t1 = t1 > 0.f ? t1 : 0.2f * t1;
    t2 = t2 > 0.f ? t2 : 0.2f * t2;
    t3 = t3 > 0.f ? t3 : 0.2f * t3;
    const float a0 = __expf(t0), a1 = __expf(t1), a2 = __expf(t2), a3 = __expf(t3);
    wsum += (a0 + a1) + (a2 + a3);
    acc += a0 * g0 + a1 * g1 + a2 * g2v + a3 * g3;
  }
  for (; i < end; ++i) {
    const int s = srcs[i];
    float t = esrc[s] + ed;
    t = t > 0.f ? t : 0.2f * t;
    const float a = __expf(t);
    wsum += a;
    if (act) acc += a * bf2f(g2b[(size_t)s * NCLASSC + lane]);
  }
  const float inv = 1.f / (wsum + 1e-16f);
  if (act) out[(size_t)n * NCLASSC + lane] = acc * inv;
}

extern "C" void kernel_launch(void* const* d_in, const int* in_sizes, int n_in,
                              void* d_out, int out_size, void* d_ws, size_t ws_size,
                              hipStream_t stream) {
  const float* x   = (const float*)d_in[0];
  const int*   ei  = (const int*)d_in[1];
  const float* W1  = (const float*)d_in[2];
  const float* b1  = (const float*)d_in[3];
  const float* B1  = (const float*)d_in[4];
  const float* cs1 = (const float*)d_in[5];
  const float* cd1 = (const float*)d_in[6];
  const float* W2  = (const float*)d_in[7];
  const float* B2  = (const float*)d_in[8];
  const float* cs2 = (const float*)d_in[9];
  const float* cd2 = (const float*)d_in[10];
  const int* srcA = ei;
  const int* dstA = ei + N_EDGESC;
  float* out = (float*)d_out;

  char* ws = (char*)d_ws;
  size_t off = 0;
  auto alloc = [&](size_t bytes) -> void* {
    void* p = ws + off;
    off += (bytes + 255) & ~(size_t)255;
    return p;
  };
  unsigned short* h1b = (unsigned short*)alloc((size_t)N_NODESC * HD1C * 2);   // bf16 gather table
  float* hact   = (float*)alloc((size_t)N_NODESC * HD1C * 4);                  // elu(agg1)
  unsigned short* g2b = (unsigned short*)alloc((size_t)N_NODESC * NCLASSC * 2);
  float* s1     = (float*)alloc((size_t)N_NODESC * NBASEC * 4);
  float* s2     = (float*)alloc((size_t)N_NODESC * NBASEC * 4);
  float* esrc1  = (float*)alloc((size_t)N_NODESC * NHEADC * 4);
  float* edst1  = (float*)alloc((size_t)N_NODESC * NHEADC * 4);
  float* esrc2  = (float*)alloc((size_t)N_NODESC * 4);
  float* edst2  = (float*)alloc((size_t)N_NODESC * 4);
  int* counts   = (int*)alloc((size_t)N_NODESC * 4);
  int* offsets  = (int*)alloc((size_t)(N_NODESC + 1) * 4);
  int* bsums    = (int*)alloc((size_t)SCAN_NB * 4);
  int* srcs_csr = (int*)alloc((size_t)N_EDGESC * 4);

  hipMemsetAsync(counts, 0, (size_t)N_NODESC * 4, stream);

  // CSR build
  hist_kernel<<<(N_EDGESC + 255) / 256, 256, 0, stream>>>(dstA, counts);
  reduce_counts<<<SCAN_NB, 256, 0, stream>>>(counts, bsums);
  scan_bsums_k<<<1, 256, 0, stream>>>(bsums);
  scan_final<<<SCAN_NB, 256, 0, stream>>>(counts, bsums, offsets);
  scatter_kernel<<<(N_EDGESC + 255) / 256, 256, 0, stream>>>(dstA, srcA, offsets, counts,
                                                             srcs_csr);

  // layer 1
  dim3 gh1((N_NODESC + 127) / 128, HD1C / 128);
  gemm128_bf16<<<gh1, 256, 0, stream>>>(x, W1, h1b, N_NODESC, HD1C, NFEATC);
  dim3 gs1((N_NODESC + 63) / 64, 1);
  gemm64<<<gs1, 256, 0, stream>>>(x, B1, s1, nullptr, N_NODESC, NBASEC, NFEATC);
  attn_scalars1<<<(N_NODESC + 255) / 256, 256, 0, stream>>>(s1, cs1, cd1, esrc1, edst1);
  agg1_kernel<<<(N_NODESC + 3) / 4, 256, 0, stream>>>(h1b, esrc1, edst1, srcs_csr, offsets,
                                                      b1, hact);

  // layer 2
  dim3 gg2((N_NODESC + 63) / 64, 1);
  gemm64<<<gg2, 256, 0, stream>>>(hact, W2, nullptr, g2b, N_NODESC, NCLASSC, HD1C);
  gemm64<<<gg2, 256, 0, stream>>>(hact, B2, s2, nullptr, N_NODESC, NBASEC, HD1C);
  attn_scalars2<<<(N_NODESC + 255) / 256, 256, 0, stream>>>(s2, cs2, cd2, esrc2, edst2);
  agg2_kernel<<<(N_NODESC + 3) / 4, 256, 0, stream>>>(g2b, esrc2, edst2, srcs_csr, offsets,
                                                      out);
}

// Round 4
// 416.836 us; speedup vs baseline: 1.1196x; 1.1196x over previous
//
#include <hip/hip_runtime.h>

#define N_NODESC 50000
#define N_EDGESC 800000
#define NFEATC 128
#define NHIDC 64
#define NHEADC 4
#define NBASEC 8
#define NCLASSC 40
#define HD1C (NHEADC * NHIDC)        // 256

__device__ inline float bf2f(unsigned short u) {
  union { unsigned int i; float f; } v;
  v.i = ((unsigned int)u) << 16;
  return v.f;
}
__device__ inline unsigned short f2bf(float x) {
  union { float f; unsigned int i; } v;
  v.f = x;
  unsigned int r = v.i + 0x7FFF + ((v.i >> 16) & 1);  // RNE
  return (unsigned short)(r >> 16);
}

// ---------------- fp32 GEMM, 128x128 tile, 8x8/thread (4+4 split frags), bf16 out --------
// fragment cols {tx*4..+3} u {64+tx*4..+3}: lanes hit 8 distinct bank-quads 2-way (free)
__global__ __launch_bounds__(256) void gemm128_bf16(const float* __restrict__ A,
                                                    const float* __restrict__ B,
                                                    unsigned short* __restrict__ Cb,
                                                    int M, int N, int K) {
  __shared__ float As[16][132];
  __shared__ float Bs[16][132];
  const int tid = threadIdx.x;
  const int tx = tid & 15;
  const int ty = tid >> 4;
  const int row0 = blockIdx.x * 128;
  const int col0 = blockIdx.y * 128;
  float acc[8][8] = {{0.f}};  // i<4: row ty*4+i; i>=4: row 64+ty*4+(i-4). cols likewise w/ tx

  for (int k0 = 0; k0 < K; k0 += 16) {
    {
      const int kk = tid & 15;
      const int r = tid >> 4;
#pragma unroll
      for (int p = 0; p < 8; ++p) {
        const int row = row0 + r + p * 16;
        float v = 0.f;
        if (row < M) v = A[(size_t)row * K + k0 + kk];
        As[kk][r + p * 16] = v;
      }
    }
    {
      const int c = tid & 127;
      const int kk0 = tid >> 7;
#pragma unroll
      for (int p = 0; p < 8; ++p) {
        const int kk = kk0 + p * 2;
        const int col = col0 + c;
        float v = 0.f;
        if (col < N) v = B[(size_t)(k0 + kk) * N + col];
        Bs[kk][c] = v;
      }
    }
    __syncthreads();
#pragma unroll
    for (int kk = 0; kk < 16; ++kk) {
      float av[8], bv[8];
      *reinterpret_cast<float4*>(&av[0]) = *reinterpret_cast<const float4*>(&As[kk][ty * 4]);
      *reinterpret_cast<float4*>(&av[4]) = *reinterpret_cast<const float4*>(&As[kk][64 + ty * 4]);
      *reinterpret_cast<float4*>(&bv[0]) = *reinterpret_cast<const float4*>(&Bs[kk][tx * 4]);
      *reinterpret_cast<float4*>(&bv[4]) = *reinterpret_cast<const float4*>(&Bs[kk][64 + tx * 4]);
#pragma unroll
      for (int i = 0; i < 8; ++i)
#pragma unroll
        for (int j = 0; j < 8; ++j) acc[i][j] += av[i] * bv[j];
    }
    __syncthreads();
  }
#pragma unroll
  for (int i = 0; i < 8; ++i) {
    const int row = row0 + ((i < 4) ? (ty * 4 + i) : (64 + ty * 4 + i - 4));
    if (row >= M) continue;
#pragma unroll
    for (int j = 0; j < 8; ++j) {
      const int col = col0 + ((j < 4) ? (tx * 4 + j) : (64 + tx * 4 + j - 4));
      if (col < N) Cb[(size_t)row * N + col] = f2bf(acc[i][j]);
    }
  }
}

// ------- fp32 GEMM, 64x64 tile, 4x4/thread; cols<ncut -> bf16 Cb, cols>=ncut -> fp32 Cf ---
__global__ __launch_bounds__(256) void gemm64s(const float* __restrict__ A,
                                               const float* __restrict__ B,
                                               unsigned short* __restrict__ Cb,
                                               float* __restrict__ Cf,
                                               int M, int N, int K, int ncut) {
  __shared__ float As[16][68];
  __shared__ float Bs[16][68];
  const int tid = threadIdx.x;
  const int tx = tid & 15;
  const int ty = tid >> 4;
  const int row0 = blockIdx.x * 64;
  const int col0 = blockIdx.y * 64;
  float acc[4][4] = {{0.f}};

  for (int k0 = 0; k0 < K; k0 += 16) {
    {
      const int kk = tid & 15;
      const int r = tid >> 4;
#pragma unroll
      for (int p = 0; p < 4; ++p) {
        const int row = row0 + r + p * 16;
        float v = 0.f;
        if (row < M) v = A[(size_t)row * K + k0 + kk];
        As[kk][r + p * 16] = v;
      }
    }
    {
      const int c = tid & 63;
      const int kk0 = tid >> 6;
#pragma unroll
      for (int p = 0; p < 4; ++p) {
        const int kk = kk0 + p * 4;
        const int col = col0 + c;
        float v = 0.f;
        if (col < N) v = B[(size_t)(k0 + kk) * N + col];
        Bs[kk][c] = v;
      }
    }
    __syncthreads();
#pragma unroll
    for (int kk = 0; kk < 16; ++kk) {
      const float4 av = *reinterpret_cast<const float4*>(&As[kk][ty * 4]);
      const float4 bv = *reinterpret_cast<const float4*>(&Bs[kk][tx * 4]);
      acc[0][0] += av.x * bv.x; acc[0][1] += av.x * bv.y; acc[0][2] += av.x * bv.z; acc[0][3] += av.x * bv.w;
      acc[1][0] += av.y * bv.x; acc[1][1] += av.y * bv.y; acc[1][2] += av.y * bv.z; acc[1][3] += av.y * bv.w;
      acc[2][0] += av.z * bv.x; acc[2][1] += av.z * bv.y; acc[2][2] += av.z * bv.z; acc[2][3] += av.z * bv.w;
      acc[3][0] += av.w * bv.x; acc[3][1] += av.w * bv.y; acc[3][2] += av.w * bv.z; acc[3][3] += av.w * bv.w;
    }
    __syncthreads();
  }
#pragma unroll
  for (int i = 0; i < 4; ++i) {
    const int row = row0 + ty * 4 + i;
    if (row >= M) continue;
#pragma unroll
    for (int j = 0; j < 4; ++j) {
      const int col = col0 + tx * 4 + j;
      if (col >= N) continue;
      if (col < ncut) Cb[(size_t)row * ncut + col] = f2bf(acc[i][j]);
      else Cf[(size_t)row * (N - ncut) + (col - ncut)] = acc[i][j];
    }
  }
}

// ---------------- concat [W2 | B2] -> WB2 [256 x 48] ----------------
__global__ void concat_w2(const float* __restrict__ W2, const float* __restrict__ B2,
                          float* __restrict__ WB2) {
  const int i = blockIdx.x * blockDim.x + threadIdx.x;
  const int tot = HD1C * (NCLASSC + NBASEC);
  if (i >= tot) return;
  const int r = i / (NCLASSC + NBASEC);
  const int c = i - r * (NCLASSC + NBASEC);
  WB2[i] = (c < NCLASSC) ? W2[(size_t)r * NCLASSC + c] : B2[(size_t)r * NBASEC + (c - NCLASSC)];
}

// ---------------- per-node attention scalars ----------------
__global__ void attn_scalars1(const float* __restrict__ s1,
                              const float* __restrict__ cs1, const float* __restrict__ cd1,
                              float* __restrict__ esrc, float* __restrict__ edst) {
  const int n = blockIdx.x * blockDim.x + threadIdx.x;
  if (n >= N_NODESC) return;
  const float* s = s1 + (size_t)n * NBASEC;
  float sb[NBASEC];
#pragma unroll
  for (int b = 0; b < NBASEC; ++b) sb[b] = s[b];
#pragma unroll
  for (int h = 0; h < NHEADC; ++h) {
    float a = 0.f, d = 0.f;
#pragma unroll
    for (int b = 0; b < NBASEC; ++b) {
      a += sb[b] * cs1[b * NHEADC + h];
      d += sb[b] * cd1[b * NHEADC + h];
    }
    esrc[n * NHEADC + h] = a;
    edst[n * NHEADC + h] = d;
  }
}

__global__ void attn_scalars2(const float* __restrict__ s2,
                              const float* __restrict__ cs2, const float* __restrict__ cd2,
                              float* __restrict__ esrc, float* __restrict__ edst) {
  const int n = blockIdx.x * blockDim.x + threadIdx.x;
  if (n >= N_NODESC) return;
  const float* s = s2 + (size_t)n * NBASEC;
  float a = 0.f, d = 0.f;
#pragma unroll
  for (int b = 0; b < NBASEC; ++b) {
    a += s[b] * cs2[b];
    d += s[b] * cd2[b];
  }
  esrc[n] = a;
  edst[n] = d;
}

// ---------------- CSR build (by destination node) ----------------
__global__ void hist_kernel(const int* __restrict__ dst, int* __restrict__ counts) {
  const int e = blockIdx.x * blockDim.x + threadIdx.x;
  if (e < N_EDGESC) atomicAdd(&counts[dst[e]], 1);
}

#define SCAN_NB ((N_NODESC + 255) / 256)   // 196

__global__ void reduce_counts(const int* __restrict__ counts, int* __restrict__ bsums) {
  __shared__ int sm[256];
  const int i = blockIdx.x * 256 + threadIdx.x;
  sm[threadIdx.x] = (i < N_NODESC) ? counts[i] : 0;
  __syncthreads();
  for (int d = 128; d > 0; d >>= 1) {
    if (threadIdx.x < (unsigned)d) sm[threadIdx.x] += sm[threadIdx.x + d];
    __syncthreads();
  }
  if (threadIdx.x == 0) bsums[blockIdx.x] = sm[0];
}

__global__ void scan_bsums_k(int* __restrict__ bsums) {
  __shared__ int sm[256];
  const int v = (threadIdx.x < SCAN_NB) ? bsums[threadIdx.x] : 0;
  sm[threadIdx.x] = v;
  __syncthreads();
  for (int d = 1; d < 256; d <<= 1) {
    const int t = (threadIdx.x >= (unsigned)d) ? sm[threadIdx.x - d] : 0;
    __syncthreads();
    sm[threadIdx.x] += t;
    __syncthreads();
  }
  if (threadIdx.x < SCAN_NB) bsums[threadIdx.x] = sm[threadIdx.x] - v;  // exclusive
}

__global__ void scan_final(const int* __restrict__ counts, const int* __restrict__ bsums,
                           int* __restrict__ offsets) {
  __shared__ int sm[256];
  const int i = blockIdx.x * 256 + threadIdx.x;
  const int v = (i < N_NODESC) ? counts[i] : 0;
  sm[threadIdx.x] = v;
  __syncthreads();
  for (int d = 1; d < 256; d <<= 1) {
    const int t = (threadIdx.x >= (unsigned)d) ? sm[threadIdx.x - d] : 0;
    __syncthreads();
    sm[threadIdx.x] += t;
    __syncthreads();
  }
  if (i < N_NODESC) offsets[i] = bsums[blockIdx.x] + sm[threadIdx.x] - v;
  if (i == 0) offsets[N_NODESC] = N_EDGESC;
}

__global__ void scatter_kernel(const int* __restrict__ dst, const int* __restrict__ src,
                               const int* __restrict__ offsets, int* __restrict__ counts,
                               int* __restrict__ srcs_csr) {
  const int e = blockIdx.x * blockDim.x + threadIdx.x;
  if (e >= N_EDGESC) return;
  const int n = dst[e];
  const int pos = offsets[n] + atomicSub(&counts[n], 1) - 1;
  srcs_csr[pos] = src[e];
}

// ---------------- layer-1 single-pass softmax-aggregate + bias + ELU ----------------
__global__ __launch_bounds__(256) void agg1_kernel(
    const unsigned short* __restrict__ h1b, const float* __restrict__ esrc,
    const float* __restrict__ edst, const int* __restrict__ srcs,
    const int* __restrict__ offsets, const float* __restrict__ bias,
    float* __restrict__ hact) {
  const int wv = threadIdx.x >> 6;
  const int lane = threadIdx.x & 63;
  const int n = blockIdx.x * 4 + wv;
  if (n >= N_NODESC) return;
  const int h = lane >> 4;
  const int f = lane << 2;
  const int beg = offsets[n], end = offsets[n + 1];
  const float ed = edst[n * NHEADC + h];

  float wsum = 0.f;
  float ax = 0.f, ay = 0.f, az = 0.f, aw = 0.f;
  int i = beg;
  for (; i + 4 <= end; i += 4) {
    const int s0 = srcs[i], s1 = srcs[i + 1], s2 = srcs[i + 2], s3 = srcs[i + 3];
    float t0 = esrc[s0 * NHEADC + h] + ed;
    float t1 = esrc[s1 * NHEADC + h] + ed;
    float t2 = esrc[s2 * NHEADC + h] + ed;
    float t3 = esrc[s3 * NHEADC + h] + ed;
    const ushort4 h0 = *reinterpret_cast<const ushort4*>(h1b + (size_t)s0 * HD1C + f);
    const ushort4 h1 = *reinterpret_cast<const ushort4*>(h1b + (size_t)s1 * HD1C + f);
    const ushort4 h2 = *reinterpret_cast<const ushort4*>(h1b + (size_t)s2 * HD1C + f);
    const ushort4 h3 = *reinterpret_cast<const ushort4*>(h1b + (size_t)s3 * HD1C + f);
    t0 = t0 > 0.f ? t0 : 0.2f * t0;
    t1 = t1 > 0.f ? t1 : 0.2f * t1;
    t2 = t2 > 0.f ? t2 : 0.2f * t2;
    t3 = t3 > 0.f ? t3 : 0.2f * t3;
    const float a0 = __expf(t0), a1 = __expf(t1), a2 = __expf(t2), a3 = __expf(t3);
    wsum += (a0 + a1) + (a2 + a3);
    ax += a0 * bf2f(h0.x) + a1 * bf2f(h1.x) + a2 * bf2f(h2.x) + a3 * bf2f(h3.x);
    ay += a0 * bf2f(h0.y) + a1 * bf2f(h1.y) + a2 * bf2f(h2.y) + a3 * bf2f(h3.y);
    az += a0 * bf2f(h0.z) + a1 * bf2f(h1.z) + a2 * bf2f(h2.z) + a3 * bf2f(h3.z);
    aw += a0 * bf2f(h0.w) + a1 * bf2f(h1.w) + a2 * bf2f(h2.w) + a3 * bf2f(h3.w);
  }
  for (; i < end; ++i) {
    const int s = srcs[i];
    float t = esrc[s * NHEADC + h] + ed;
    t = t > 0.f ? t : 0.2f * t;
    const float a = __expf(t);
    const ushort4 hv = *reinterpret_cast<const ushort4*>(h1b + (size_t)s * HD1C + f);
    wsum += a;
    ax += a * bf2f(hv.x); ay += a * bf2f(hv.y); az += a * bf2f(hv.z); aw += a * bf2f(hv.w);
  }
  const float inv = 1.f / (wsum + 1e-16f);
  const float4 bb = *reinterpret_cast<const float4*>(bias + f);
  float4 o;
  o.x = ax * inv + bb.x; o.x = o.x > 0.f ? o.x : __expf(o.x) - 1.f;
  o.y = ay * inv + bb.y; o.y = o.y > 0.f ? o.y : __expf(o.y) - 1.f;
  o.z = az * inv + bb.z; o.z = o.z > 0.f ? o.z : __expf(o.z) - 1.f;
  o.w = aw * inv + bb.w; o.w = o.w > 0.f ? o.w : __expf(o.w) - 1.f;
  *reinterpret_cast<float4*>(hact + (size_t)n * HD1C + f) = o;
}

// ---------------- layer-2 single-pass softmax-aggregate (1 head, 40 classes) ----------------
__global__ __launch_bounds__(256) void agg2_kernel(
    const unsigned short* __restrict__ g2b, const float* __restrict__ esrc,
    const float* __restrict__ edst, const int* __restrict__ srcs,
    const int* __restrict__ offsets, float* __restrict__ out) {
  const int wv = threadIdx.x >> 6;
  const int lane = threadIdx.x & 63;
  const int n = blockIdx.x * 4 + wv;
  if (n >= N_NODESC) return;
  const int beg = offsets[n], end = offsets[n + 1];
  const float ed = edst[n];

  float wsum = 0.f, acc = 0.f;
  const bool act = lane < NCLASSC;
  int i = beg;
  for (; i + 4 <= end; i += 4) {
    const int s0 = srcs[i], s1 = srcs[i + 1], s2 = srcs[i + 2], s3 = srcs[i + 3];
    float t0 = esrc[s0] + ed, t1 = esrc[s1] + ed, t2 = esrc[s2] + ed, t3 = esrc[s3] + ed;
    float g0 = 0.f, g1 = 0.f, g2v = 0.f, g3 = 0.f;
    if (act) {
      g0 = bf2f(g2b[(size_t)s0 * NCLASSC + lane]);
      g1 = bf2f(g2b[(size_t)s1 * NCLASSC + lane]);
      g2v = bf2f(g2b[(size_t)s2 * NCLASSC + lane]);
      g3 = bf2f(g2b[(size_t)s3 * NCLASSC + lane]);
    }
    t0 = t0 > 0.f ? t0 : 0.2f * t0;
    t1 = t1 > 0.f ? t1 : 0.2f * t1;
    t2 = t2 > 0.f ? t2 : 0.2f * t2;
    t3 = t3 > 0.f ? t3 : 0.2f * t3;
    const float a0 = __expf(t0), a1 = __expf(t1), a2 = __expf(t2), a3 = __expf(t3);
    wsum += (a0 + a1) + (a2 + a3);
    acc += a0 * g0 + a1 * g1 + a2 * g2v + a3 * g3;
  }
  for (; i < end; ++i) {
    const int s = srcs[i];
    float t = esrc[s] + ed;
    t = t > 0.f ? t : 0.2f * t;
    const float a = __expf(t);
    wsum += a;
    if (act) acc += a * bf2f(g2b[(size_t)s * NCLASSC + lane]);
  }
  const float inv = 1.f / (wsum + 1e-16f);
  if (act) out[(size_t)n * NCLASSC + lane] = acc * inv;
}

extern "C" void kernel_launch(void* const* d_in, const int* in_sizes, int n_in,
                              void* d_out, int out_size, void* d_ws, size_t ws_size,
                              hipStream_t stream) {
  const float* x   = (const float*)d_in[0];
  const int*   ei  = (const int*)d_in[1];
  const float* W1  = (const float*)d_in[2];
  const float* b1  = (const float*)d_in[3];
  const float* B1  = (const float*)d_in[4];
  const float* cs1 = (const float*)d_in[5];
  const float* cd1 = (const float*)d_in[6];
  const float* W2  = (const float*)d_in[7];
  const float* B2  = (const float*)d_in[8];
  const float* cs2 = (const float*)d_in[9];
  const float* cd2 = (const float*)d_in[10];
  const int* srcA = ei;
  const int* dstA = ei + N_EDGESC;
  float* out = (float*)d_out;

  char* ws = (char*)d_ws;
  size_t off = 0;
  auto alloc = [&](size_t bytes) -> void* {
    void* p = ws + off;
    off += (bytes + 255) & ~(size_t)255;
    return p;
  };
  unsigned short* h1b = (unsigned short*)alloc((size_t)N_NODESC * HD1C * 2);
  float* hact   = (float*)alloc((size_t)N_NODESC * HD1C * 4);
  unsigned short* g2b = (unsigned short*)alloc((size_t)N_NODESC * NCLASSC * 2);
  float* s1     = (float*)alloc((size_t)N_NODESC * NBASEC * 4);
  float* s2     = (float*)alloc((size_t)N_NODESC * NBASEC * 4);
  float* esrc1  = (float*)alloc((size_t)N_NODESC * NHEADC * 4);
  float* edst1  = (float*)alloc((size_t)N_NODESC * NHEADC * 4);
  float* esrc2  = (float*)alloc((size_t)N_NODESC * 4);
  float* edst2  = (float*)alloc((size_t)N_NODESC * 4);
  float* WB2    = (float*)alloc((size_t)HD1C * (NCLASSC + NBASEC) * 4);
  int* counts   = (int*)alloc((size_t)N_NODESC * 4);
  int* offsets  = (int*)alloc((size_t)(N_NODESC + 1) * 4);
  int* bsums    = (int*)alloc((size_t)SCAN_NB * 4);
  int* srcs_csr = (int*)alloc((size_t)N_EDGESC * 4);

  hipMemsetAsync(counts, 0, (size_t)N_NODESC * 4, stream);

  // CSR build
  hist_kernel<<<(N_EDGESC + 255) / 256, 256, 0, stream>>>(dstA, counts);
  reduce_counts<<<SCAN_NB, 256, 0, stream>>>(counts, bsums);
  scan_bsums_k<<<1, 256, 0, stream>>>(bsums);
  scan_final<<<SCAN_NB, 256, 0, stream>>>(counts, bsums, offsets);
  scatter_kernel<<<(N_EDGESC + 255) / 256, 256, 0, stream>>>(dstA, srcA, offsets, counts,
                                                             srcs_csr);
  concat_w2<<<(HD1C * (NCLASSC + NBASEC) + 255) / 256, 256, 0, stream>>>(W2, B2, WB2);

  // layer 1
  dim3 gh1((N_NODESC + 127) / 128, HD1C / 128);
  gemm128_bf16<<<gh1, 256, 0, stream>>>(x, W1, h1b, N_NODESC, HD1C, NFEATC);
  dim3 gs1((N_NODESC + 63) / 64, 1);
  gemm64s<<<gs1, 256, 0, stream>>>(x, B1, nullptr, s1, N_NODESC, NBASEC, NFEATC, 0);
  attn_scalars1<<<(N_NODESC + 255) / 256, 256, 0, stream>>>(s1, cs1, cd1, esrc1, edst1);
  agg1_kernel<<<(N_NODESC + 3) / 4, 256, 0, stream>>>(h1b, esrc1, edst1, srcs_csr, offsets,
                                                      b1, hact);

  // layer 2: one pass over hact computes [g2b | s2]
  dim3 gg2((N_NODESC + 63) / 64, 1);
  gemm64s<<<gg2, 256, 0, stream>>>(hact, WB2, g2b, s2, N_NODESC, NCLASSC + NBASEC, HD1C,
                                   NCLASSC);
  attn_scalars2<<<(N_NODESC + 255) / 256, 256, 0, stream>>>(s2, cs2, cd2, esrc2, edst2);
  agg2_kernel<<<(N_NODESC + 3) / 4, 256, 0, stream>>>(g2b, esrc2, edst2, srcs_csr, offsets,
                                                      out);
}

// Round 5
// 323.963 us; speedup vs baseline: 1.4406x; 1.2867x over previous
//
#include <hip/hip_runtime.h>

#define N_NODESC 50000
#define N_EDGESC 800000
#define NFEATC 128
#define NHIDC 64
#define NHEADC 4
#define NBASEC 8
#define NCLASSC 40
#define HD1C (NHEADC * NHIDC)        // 256
#define W1TROWS 320                  // 256 + 8, padded to 64-multiple
#define W2TROWS 64                   // 40 + 8, padded

typedef __attribute__((ext_vector_type(8))) short bf16x8;
typedef __attribute__((ext_vector_type(4))) float f32x4;

__device__ inline float bf2f(unsigned short u) {
  union { unsigned int i; float f; } v;
  v.i = ((unsigned int)u) << 16;
  return v.f;
}
__device__ inline unsigned short f2bf(float x) {
  union { float f; unsigned int i; } v;
  v.f = x;
  unsigned int r = v.i + 0x7FFF + ((v.i >> 16) & 1);  // RNE
  return (unsigned short)(r >> 16);
}

// ---------------- bf16 MFMA GEMM, B^T input, direct-from-global ----------------
// A [M][K] bf16 row-major; BT [npad][K] bf16 row-major (npad >= gridDim.y*64, zero-padded).
// Block = 4 waves stacked in rows (256 rows); each wave computes a 64x64 tile via
// 4x4 mfma_f32_16x16x32_bf16. Epilogue: col<ncut -> bf16 Cb (stride ncut),
// col in [ncut,ncols) -> fp32 Cf (stride ncols-ncut).
__global__ __launch_bounds__(256) void mfma_gemm_bt(
    const unsigned short* __restrict__ A, const unsigned short* __restrict__ BT,
    int M, int K, int ncols, int ncut,
    unsigned short* __restrict__ Cb, float* __restrict__ Cf) {
  const int wave = threadIdx.x >> 6;
  const int lane = threadIdx.x & 63;
  const int m0 = blockIdx.x * 256 + wave * 64;
  const int n0 = blockIdx.y * 64;
  const int lm = lane & 15;          // A row-in-16 / B col-in-16
  const int kq = (lane >> 4) * 8;    // k sub-offset (quad*8)
  f32x4 acc[4][4] = {};

  for (int k0 = 0; k0 < K; k0 += 32) {
    bf16x8 af[4], bfr[4];
#pragma unroll
    for (int mi = 0; mi < 4; ++mi) {
      int row = m0 + mi * 16 + lm;
      row = row < M ? row : M - 1;   // clamp; surplus rows never stored
      af[mi] = *reinterpret_cast<const bf16x8*>(A + (size_t)row * K + k0 + kq);
    }
#pragma unroll
    for (int ni = 0; ni < 4; ++ni) {
      const int col = n0 + ni * 16 + lm;
      bfr[ni] = *reinterpret_cast<const bf16x8*>(BT + (size_t)col * K + k0 + kq);
    }
#pragma unroll
    for (int mi = 0; mi < 4; ++mi)
#pragma unroll
      for (int ni = 0; ni < 4; ++ni)
        acc[mi][ni] = __builtin_amdgcn_mfma_f32_16x16x32_bf16(af[mi], bfr[ni], acc[mi][ni],
                                                              0, 0, 0);
  }
  const int cw = ncols - ncut;
#pragma unroll
  for (int mi = 0; mi < 4; ++mi) {
#pragma unroll
    for (int r = 0; r < 4; ++r) {
      const int row = m0 + mi * 16 + (lane >> 4) * 4 + r;
      if (row >= M) continue;
#pragma unroll
      for (int ni = 0; ni < 4; ++ni) {
        const int col = n0 + ni * 16 + lm;
        if (col >= ncols) continue;
        const float v = acc[mi][ni][r];
        if (col < ncut) Cb[(size_t)row * ncut + col] = f2bf(v);
        else Cf[(size_t)row * cw + (col - ncut)] = v;
      }
    }
  }
}

// ---------------- fp32 -> bf16 convert (x4 vectorized) ----------------
__global__ void cvt_bf16(const float* __restrict__ in, unsigned short* __restrict__ out,
                         int n4) {
  const int i = blockIdx.x * blockDim.x + threadIdx.x;
  if (i >= n4) return;
  const float4 v = reinterpret_cast<const float4*>(in)[i];
  ushort4 o;
  o.x = f2bf(v.x); o.y = f2bf(v.y); o.z = f2bf(v.z); o.w = f2bf(v.w);
  reinterpret_cast<ushort4*>(out)[i] = o;
}

// ---------------- weight transposes -> bf16 [npad][K], zero-padded ----------------
__global__ void build_w1t(const float* __restrict__ W1, const float* __restrict__ B1,
                          unsigned short* __restrict__ W1T) {
  const int i = blockIdx.x * blockDim.x + threadIdx.x;
  if (i >= W1TROWS * NFEATC) return;
  const int n = i / NFEATC, k = i - n * NFEATC;
  float v = 0.f;
  if (n < HD1C) v = W1[(size_t)k * HD1C + n];
  else if (n < HD1C + NBASEC) v = B1[(size_t)k * NBASEC + (n - HD1C)];
  W1T[i] = f2bf(v);
}

__global__ void build_w2t(const float* __restrict__ W2, const float* __restrict__ B2,
                          unsigned short* __restrict__ W2T) {
  const int i = blockIdx.x * blockDim.x + threadIdx.x;
  if (i >= W2TROWS * HD1C) return;
  const int n = i / HD1C, k = i - n * HD1C;
  float v = 0.f;
  if (n < NCLASSC) v = W2[(size_t)k * NCLASSC + n];
  else if (n < NCLASSC + NBASEC) v = B2[(size_t)k * NBASEC + (n - NCLASSC)];
  W2T[i] = f2bf(v);
}

// ---------------- per-node attention scalars ----------------
__global__ void attn_scalars1(const float* __restrict__ s1,
                              const float* __restrict__ cs1, const float* __restrict__ cd1,
                              float* __restrict__ esrc, float* __restrict__ edst) {
  const int n = blockIdx.x * blockDim.x + threadIdx.x;
  if (n >= N_NODESC) return;
  const float* s = s1 + (size_t)n * NBASEC;
  float sb[NBASEC];
#pragma unroll
  for (int b = 0; b < NBASEC; ++b) sb[b] = s[b];
#pragma unroll
  for (int h = 0; h < NHEADC; ++h) {
    float a = 0.f, d = 0.f;
#pragma unroll
    for (int b = 0; b < NBASEC; ++b) {
      a += sb[b] * cs1[b * NHEADC + h];
      d += sb[b] * cd1[b * NHEADC + h];
    }
    esrc[n * NHEADC + h] = a;
    edst[n * NHEADC + h] = d;
  }
}

__global__ void attn_scalars2(const float* __restrict__ s2,
                              const float* __restrict__ cs2, const float* __restrict__ cd2,
                              float* __restrict__ esrc, float* __restrict__ edst) {
  const int n = blockIdx.x * blockDim.x + threadIdx.x;
  if (n >= N_NODESC) return;
  const float* s = s2 + (size_t)n * NBASEC;
  float a = 0.f, d = 0.f;
#pragma unroll
  for (int b = 0; b < NBASEC; ++b) {
    a += s[b] * cs2[b];
    d += s[b] * cd2[b];
  }
  esrc[n] = a;
  edst[n] = d;
}

// ---------------- CSR build (by destination node) ----------------
__global__ void hist_kernel(const int* __restrict__ dst, int* __restrict__ counts) {
  const int e = blockIdx.x * blockDim.x + threadIdx.x;
  if (e < N_EDGESC) atomicAdd(&counts[dst[e]], 1);
}

#define SCAN_NB ((N_NODESC + 255) / 256)   // 196

__global__ void reduce_counts(const int* __restrict__ counts, int* __restrict__ bsums) {
  __shared__ int sm[256];
  const int i = blockIdx.x * 256 + threadIdx.x;
  sm[threadIdx.x] = (i < N_NODESC) ? counts[i] : 0;
  __syncthreads();
  for (int d = 128; d > 0; d >>= 1) {
    if (threadIdx.x < (unsigned)d) sm[threadIdx.x] += sm[threadIdx.x + d];
    __syncthreads();
  }
  if (threadIdx.x == 0) bsums[blockIdx.x] = sm[0];
}

__global__ void scan_bsums_k(int* __restrict__ bsums) {
  __shared__ int sm[256];
  const int v = (threadIdx.x < SCAN_NB) ? bsums[threadIdx.x] : 0;
  sm[threadIdx.x] = v;
  __syncthreads();
  for (int d = 1; d < 256; d <<= 1) {
    const int t = (threadIdx.x >= (unsigned)d) ? sm[threadIdx.x - d] : 0;
    __syncthreads();
    sm[threadIdx.x] += t;
    __syncthreads();
  }
  if (threadIdx.x < SCAN_NB) bsums[threadIdx.x] = sm[threadIdx.x] - v;  // exclusive
}

__global__ void scan_final(const int* __restrict__ counts, const int* __restrict__ bsums,
                           int* __restrict__ offsets) {
  __shared__ int sm[256];
  const int i = blockIdx.x * 256 + threadIdx.x;
  const int v = (i < N_NODESC) ? counts[i] : 0;
  sm[threadIdx.x] = v;
  __syncthreads();
  for (int d = 1; d < 256; d <<= 1) {
    const int t = (threadIdx.x >= (unsigned)d) ? sm[threadIdx.x - d] : 0;
    __syncthreads();
    sm[threadIdx.x] += t;
    __syncthreads();
  }
  if (i < N_NODESC) offsets[i] = bsums[blockIdx.x] + sm[threadIdx.x] - v;
  if (i == 0) offsets[N_NODESC] = N_EDGESC;
}

__global__ void scatter_kernel(const int* __restrict__ dst, const int* __restrict__ src,
                               const int* __restrict__ offsets, int* __restrict__ counts,
                               int* __restrict__ srcs_csr) {
  const int e = blockIdx.x * blockDim.x + threadIdx.x;
  if (e >= N_EDGESC) return;
  const int n = dst[e];
  const int pos = offsets[n] + atomicSub(&counts[n], 1) - 1;
  srcs_csr[pos] = src[e];
}

// ---------------- layer-1 single-pass softmax-aggregate + bias + ELU -> bf16 ----------------
__global__ __launch_bounds__(256) void agg1_kernel(
    const unsigned short* __restrict__ h1b, const float* __restrict__ esrc,
    const float* __restrict__ edst, const int* __restrict__ srcs,
    const int* __restrict__ offsets, const float* __restrict__ bias,
    unsigned short* __restrict__ hactb) {
  const int wv = threadIdx.x >> 6;
  const int lane = threadIdx.x & 63;
  const int n = blockIdx.x * 4 + wv;
  if (n >= N_NODESC) return;
  const int h = lane >> 4;
  const int f = lane << 2;
  const int beg = offsets[n], end = offsets[n + 1];
  const float ed = edst[n * NHEADC + h];

  float wsum = 0.f;
  float ax = 0.f, ay = 0.f, az = 0.f, aw = 0.f;
  int i = beg;
  for (; i + 4 <= end; i += 4) {
    const int s0 = srcs[i], s1 = srcs[i + 1], s2 = srcs[i + 2], s3 = srcs[i + 3];
    float t0 = esrc[s0 * NHEADC + h] + ed;
    float t1 = esrc[s1 * NHEADC + h] + ed;
    float t2 = esrc[s2 * NHEADC + h] + ed;
    float t3 = esrc[s3 * NHEADC + h] + ed;
    const ushort4 h0 = *reinterpret_cast<const ushort4*>(h1b + (size_t)s0 * HD1C + f);
    const ushort4 h1 = *reinterpret_cast<const ushort4*>(h1b + (size_t)s1 * HD1C + f);
    const ushort4 h2 = *reinterpret_cast<const ushort4*>(h1b + (size_t)s2 * HD1C + f);
    const ushort4 h3 = *reinterpret_cast<const ushort4*>(h1b + (size_t)s3 * HD1C + f);
    t0 = t0 > 0.f ? t0 : 0.2f * t0;
    t1 = t1 > 0.f ? t1 : 0.2f * t1;
    t2 = t2 > 0.f ? t2 : 0.2f * t2;
    t3 = t3 > 0.f ? t3 : 0.2f * t3;
    const float a0 = __expf(t0), a1 = __expf(t1), a2 = __expf(t2), a3 = __expf(t3);
    wsum += (a0 + a1) + (a2 + a3);
    ax += a0 * bf2f(h0.x) + a1 * bf2f(h1.x) + a2 * bf2f(h2.x) + a3 * bf2f(h3.x);
    ay += a0 * bf2f(h0.y) + a1 * bf2f(h1.y) + a2 * bf2f(h2.y) + a3 * bf2f(h3.y);
    az += a0 * bf2f(h0.z) + a1 * bf2f(h1.z) + a2 * bf2f(h2.z) + a3 * bf2f(h3.z);
    aw += a0 * bf2f(h0.w) + a1 * bf2f(h1.w) + a2 * bf2f(h2.w) + a3 * bf2f(h3.w);
  }
  for (; i < end; ++i) {
    const int s = srcs[i];
    float t = esrc[s * NHEADC + h] + ed;
    t = t > 0.f ? t : 0.2f * t;
    const float a = __expf(t);
    const ushort4 hv = *reinterpret_cast<const ushort4*>(h1b + (size_t)s * HD1C + f);
    wsum += a;
    ax += a * bf2f(hv.x); ay += a * bf2f(hv.y); az += a * bf2f(hv.z); aw += a * bf2f(hv.w);
  }
  const float inv = 1.f / (wsum + 1e-16f);
  const float4 bb = *reinterpret_cast<const float4*>(bias + f);
  float vx = ax * inv + bb.x; vx = vx > 0.f ? vx : __expf(vx) - 1.f;
  float vy = ay * inv + bb.y; vy = vy > 0.f ? vy : __expf(vy) - 1.f;
  float vz = az * inv + bb.z; vz = vz > 0.f ? vz : __expf(vz) - 1.f;
  float vw = aw * inv + bb.w; vw = vw > 0.f ? vw : __expf(vw) - 1.f;
  ushort4 o;
  o.x = f2bf(vx); o.y = f2bf(vy); o.z = f2bf(vz); o.w = f2bf(vw);
  *reinterpret_cast<ushort4*>(hactb + (size_t)n * HD1C + f) = o;
}

// ---------------- layer-2 single-pass softmax-aggregate (1 head, 40 classes) ----------------
__global__ __launch_bounds__(256) void agg2_kernel(
    const unsigned short* __restrict__ g2b, const float* __restrict__ esrc,
    const float* __restrict__ edst, const int* __restrict__ srcs,
    const int* __restrict__ offsets, float* __restrict__ out) {
  const int wv = threadIdx.x >> 6;
  const int lane = threadIdx.x & 63;
  const int n = blockIdx.x * 4 + wv;
  if (n >= N_NODESC) return;
  const int beg = offsets[n], end = offsets[n + 1];
  const float ed = edst[n];

  float wsum = 0.f, acc = 0.f;
  const bool act = lane < NCLASSC;
  int i = beg;
  for (; i + 4 <= end; i += 4) {
    const int s0 = srcs[i], s1 = srcs[i + 1], s2 = srcs[i + 2], s3 = srcs[i + 3];
    float t0 = esrc[s0] + ed, t1 = esrc[s1] + ed, t2 = esrc[s2] + ed, t3 = esrc[s3] + ed;
    float g0 = 0.f, g1 = 0.f, g2v = 0.f, g3 = 0.f;
    if (act) {
      g0 = bf2f(g2b[(size_t)s0 * NCLASSC + lane]);
      g1 = bf2f(g2b[(size_t)s1 * NCLASSC + lane]);
      g2v = bf2f(g2b[(size_t)s2 * NCLASSC + lane]);
      g3 = bf2f(g2b[(size_t)s3 * NCLASSC + lane]);
    }
    t0 = t0 > 0.f ? t0 : 0.2f * t0;
    t1 = t1 > 0.f ? t1 : 0.2f * t1;
    t2 = t2 > 0.f ? t2 : 0.2f * t2;
    t3 = t3 > 0.f ? t3 : 0.2f * t3;
    const float a0 = __expf(t0), a1 = __expf(t1), a2 = __expf(t2), a3 = __expf(t3);
    wsum += (a0 + a1) + (a2 + a3);
    acc += a0 * g0 + a1 * g1 + a2 * g2v + a3 * g3;
  }
  for (; i < end; ++i) {
    const int s = srcs[i];
    float t = esrc[s] + ed;
    t = t > 0.f ? t : 0.2f * t;
    const float a = __expf(t);
    wsum += a;
    if (act) acc += a * bf2f(g2b[(size_t)s * NCLASSC + lane]);
  }
  const float inv = 1.f / (wsum + 1e-16f);
  if (act) out[(size_t)n * NCLASSC + lane] = acc * inv;
}

extern "C" void kernel_launch(void* const* d_in, const int* in_sizes, int n_in,
                              void* d_out, int out_size, void* d_ws, size_t ws_size,
                              hipStream_t stream) {
  const float* x   = (const float*)d_in[0];
  const int*   ei  = (const int*)d_in[1];
  const float* W1  = (const float*)d_in[2];
  const float* b1  = (const float*)d_in[3];
  const float* B1  = (const float*)d_in[4];
  const float* cs1 = (const float*)d_in[5];
  const float* cd1 = (const float*)d_in[6];
  const float* W2  = (const float*)d_in[7];
  const float* B2  = (const float*)d_in[8];
  const float* cs2 = (const float*)d_in[9];
  const float* cd2 = (const float*)d_in[10];
  const int* srcA = ei;
  const int* dstA = ei + N_EDGESC;
  float* out = (float*)d_out;

  char* ws = (char*)d_ws;
  size_t off = 0;
  auto alloc = [&](size_t bytes) -> void* {
    void* p = ws + off;
    off += (bytes + 255) & ~(size_t)255;
    return p;
  };
  unsigned short* xb    = (unsigned short*)alloc((size_t)N_NODESC * NFEATC * 2);
  unsigned short* h1b   = (unsigned short*)alloc((size_t)N_NODESC * HD1C * 2);
  unsigned short* hactb = (unsigned short*)alloc((size_t)N_NODESC * HD1C * 2);
  unsigned short* g2b   = (unsigned short*)alloc((size_t)N_NODESC * NCLASSC * 2);
  unsigned short* W1T   = (unsigned short*)alloc((size_t)W1TROWS * NFEATC * 2);
  unsigned short* W2T   = (unsigned short*)alloc((size_t)W2TROWS * HD1C * 2);
  float* s1     = (float*)alloc((size_t)N_NODESC * NBASEC * 4);
  float* s2     = (float*)alloc((size_t)N_NODESC * NBASEC * 4);
  float* esrc1  = (float*)alloc((size_t)N_NODESC * NHEADC * 4);
  float* edst1  = (float*)alloc((size_t)N_NODESC * NHEADC * 4);
  float* esrc2  = (float*)alloc((size_t)N_NODESC * 4);
  float* edst2  = (float*)alloc((size_t)N_NODESC * 4);
  int* counts   = (int*)alloc((size_t)N_NODESC * 4);
  int* offsets  = (int*)alloc((size_t)(N_NODESC + 1) * 4);
  int* bsums    = (int*)alloc((size_t)SCAN_NB * 4);
  int* srcs_csr = (int*)alloc((size_t)N_EDGESC * 4);

  hipMemsetAsync(counts, 0, (size_t)N_NODESC * 4, stream);

  // CSR build
  hist_kernel<<<(N_EDGESC + 255) / 256, 256, 0, stream>>>(dstA, counts);
  reduce_counts<<<SCAN_NB, 256, 0, stream>>>(counts, bsums);
  scan_bsums_k<<<1, 256, 0, stream>>>(bsums);
  scan_final<<<SCAN_NB, 256, 0, stream>>>(counts, bsums, offsets);
  scatter_kernel<<<(N_EDGESC + 255) / 256, 256, 0, stream>>>(dstA, srcA, offsets, counts,
                                                             srcs_csr);

  // weight prep + x conversion
  cvt_bf16<<<(N_NODESC * NFEATC / 4 + 255) / 256, 256, 0, stream>>>(x, xb,
                                                                    N_NODESC * NFEATC / 4);
  build_w1t<<<(W1TROWS * NFEATC + 255) / 256, 256, 0, stream>>>(W1, B1, W1T);
  build_w2t<<<(W2TROWS * HD1C + 255) / 256, 256, 0, stream>>>(W2, B2, W2T);

  // layer 1: [h1b | s1] = x @ [W1 | B1]  (MFMA)
  dim3 gg1((N_NODESC + 255) / 256, W1TROWS / 64);
  mfma_gemm_bt<<<gg1, 256, 0, stream>>>(xb, W1T, N_NODESC, NFEATC, HD1C + NBASEC, HD1C,
                                        h1b, s1);
  attn_scalars1<<<(N_NODESC + 255) / 256, 256, 0, stream>>>(s1, cs1, cd1, esrc1, edst1);
  agg1_kernel<<<(N_NODESC + 3) / 4, 256, 0, stream>>>(h1b, esrc1, edst1, srcs_csr, offsets,
                                                      b1, hactb);

  // layer 2: [g2b | s2] = hact @ [W2 | B2]  (MFMA)
  dim3 gg2((N_NODESC + 255) / 256, W2TROWS / 64);
  mfma_gemm_bt<<<gg2, 256, 0, stream>>>(hactb, W2T, N_NODESC, HD1C, NCLASSC + NBASEC,
                                        NCLASSC, g2b, s2);
  attn_scalars2<<<(N_NODESC + 255) / 256, 256, 0, stream>>>(s2, cs2, cd2, esrc2, edst2);
  agg2_kernel<<<(N_NODESC + 3) / 4, 256, 0, stream>>>(g2b, esrc2, edst2, srcs_csr, offsets,
                                                      out);
}

// Round 6
// 316.255 us; speedup vs baseline: 1.4757x; 1.0244x over previous
//
#include <hip/hip_runtime.h>

#define N_NODESC 50000
#define N_EDGESC 800000
#define NFEATC 128
#define NHIDC 64
#define NHEADC 4
#define NBASEC 8
#define NCLASSC 40
#define HD1C (NHEADC * NHIDC)        // 256
#define W1TROWS 320                  // 256 + 8, padded to 64-multiple
#define W2TROWS 64                   // 40 + 8, padded

typedef __attribute__((ext_vector_type(8))) short bf16x8;
typedef __attribute__((ext_vector_type(4))) float f32x4;

__device__ inline float bf2f(unsigned short u) {
  union { unsigned int i; float f; } v;
  v.i = ((unsigned int)u) << 16;
  return v.f;
}
__device__ inline float blo(unsigned int u) {
  union { unsigned int i; float f; } v; v.i = u << 16; return v.f;
}
__device__ inline float bhi(unsigned int u) {
  union { unsigned int i; float f; } v; v.i = u & 0xffff0000u; return v.f;
}
__device__ inline unsigned short f2bf(float x) {
  union { float f; unsigned int i; } v;
  v.f = x;
  unsigned int r = v.i + 0x7FFF + ((v.i >> 16) & 1);  // RNE
  return (unsigned short)(r >> 16);
}

// ---------------- bf16 MFMA GEMM, B^T input, direct-from-global ----------------
__global__ __launch_bounds__(256) void mfma_gemm_bt(
    const unsigned short* __restrict__ A, const unsigned short* __restrict__ BT,
    int M, int K, int ncols, int ncut,
    unsigned short* __restrict__ Cb, float* __restrict__ Cf) {
  const int wave = threadIdx.x >> 6;
  const int lane = threadIdx.x & 63;
  const int m0 = blockIdx.x * 256 + wave * 64;
  const int n0 = blockIdx.y * 64;
  const int lm = lane & 15;
  const int kq = (lane >> 4) * 8;
  f32x4 acc[4][4] = {};

  for (int k0 = 0; k0 < K; k0 += 32) {
    bf16x8 af[4], bfr[4];
#pragma unroll
    for (int mi = 0; mi < 4; ++mi) {
      int row = m0 + mi * 16 + lm;
      row = row < M ? row : M - 1;
      af[mi] = *reinterpret_cast<const bf16x8*>(A + (size_t)row * K + k0 + kq);
    }
#pragma unroll
    for (int ni = 0; ni < 4; ++ni) {
      const int col = n0 + ni * 16 + lm;
      bfr[ni] = *reinterpret_cast<const bf16x8*>(BT + (size_t)col * K + k0 + kq);
    }
#pragma unroll
    for (int mi = 0; mi < 4; ++mi)
#pragma unroll
      for (int ni = 0; ni < 4; ++ni)
        acc[mi][ni] = __builtin_amdgcn_mfma_f32_16x16x32_bf16(af[mi], bfr[ni], acc[mi][ni],
                                                              0, 0, 0);
  }
  const int cw = ncols - ncut;
#pragma unroll
  for (int mi = 0; mi < 4; ++mi) {
#pragma unroll
    for (int r = 0; r < 4; ++r) {
      const int row = m0 + mi * 16 + (lane >> 4) * 4 + r;
      if (row >= M) continue;
#pragma unroll
      for (int ni = 0; ni < 4; ++ni) {
        const int col = n0 + ni * 16 + lm;
        if (col >= ncols) continue;
        const float v = acc[mi][ni][r];
        if (col < ncut) Cb[(size_t)row * ncut + col] = f2bf(v);
        else Cf[(size_t)row * cw + (col - ncut)] = v;
      }
    }
  }
}

// ---------------- fused prep: cvt x->bf16 | W1T | W2T | dst histogram ----------------
#define CVT_NB ((N_NODESC * NFEATC / 4 + 255) / 256)            // 6250
#define W1T_NB ((W1TROWS * NFEATC + 255) / 256)                 // 160
#define W2T_NB ((W2TROWS * HD1C + 255) / 256)                   // 64
#define HIST_NB ((N_EDGESC + 255) / 256)                        // 3125
#define PREP_NB (CVT_NB + W1T_NB + W2T_NB + HIST_NB)

__global__ __launch_bounds__(256) void prep_kernel(
    const float* __restrict__ x, unsigned short* __restrict__ xb,
    const float* __restrict__ W1, const float* __restrict__ B1,
    unsigned short* __restrict__ W1T,
    const float* __restrict__ W2, const float* __restrict__ B2,
    unsigned short* __restrict__ W2T,
    const int* __restrict__ dst, int* __restrict__ counts) {
  int b = blockIdx.x;
  if (b < CVT_NB) {
    const int i = b * 256 + threadIdx.x;
    if (i < N_NODESC * NFEATC / 4) {
      const float4 v = reinterpret_cast<const float4*>(x)[i];
      ushort4 o;
      o.x = f2bf(v.x); o.y = f2bf(v.y); o.z = f2bf(v.z); o.w = f2bf(v.w);
      reinterpret_cast<ushort4*>(xb)[i] = o;
    }
    return;
  }
  b -= CVT_NB;
  if (b < W1T_NB) {
    const int i = b * 256 + threadIdx.x;
    if (i < W1TROWS * NFEATC) {
      const int n = i / NFEATC, k = i - n * NFEATC;
      float v = 0.f;
      if (n < HD1C) v = W1[(size_t)k * HD1C + n];
      else if (n < HD1C + NBASEC) v = B1[(size_t)k * NBASEC + (n - HD1C)];
      W1T[i] = f2bf(v);
    }
    return;
  }
  b -= W1T_NB;
  if (b < W2T_NB) {
    const int i = b * 256 + threadIdx.x;
    if (i < W2TROWS * HD1C) {
      const int n = i / HD1C, k = i - n * HD1C;
      float v = 0.f;
      if (n < NCLASSC) v = W2[(size_t)k * NCLASSC + n];
      else if (n < NCLASSC + NBASEC) v = B2[(size_t)k * NBASEC + (n - NCLASSC)];
      W2T[i] = f2bf(v);
    }
    return;
  }
  b -= W2T_NB;
  {
    const int e = b * 256 + threadIdx.x;
    if (e < N_EDGESC) atomicAdd(&counts[dst[e]], 1);
  }
}

// ---------------- per-node attention scalars ----------------
__global__ void attn_scalars1(const float* __restrict__ s1,
                              const float* __restrict__ cs1, const float* __restrict__ cd1,
                              float* __restrict__ esrc, float* __restrict__ edst) {
  const int n = blockIdx.x * blockDim.x + threadIdx.x;
  if (n >= N_NODESC) return;
  const float* s = s1 + (size_t)n * NBASEC;
  float sb[NBASEC];
#pragma unroll
  for (int b = 0; b < NBASEC; ++b) sb[b] = s[b];
#pragma unroll
  for (int h = 0; h < NHEADC; ++h) {
    float a = 0.f, d = 0.f;
#pragma unroll
    for (int b = 0; b < NBASEC; ++b) {
      a += sb[b] * cs1[b * NHEADC + h];
      d += sb[b] * cd1[b * NHEADC + h];
    }
    esrc[n * NHEADC + h] = a;
    edst[n * NHEADC + h] = d;
  }
}

__global__ void attn_scalars2(const float* __restrict__ s2,
                              const float* __restrict__ cs2, const float* __restrict__ cd2,
                              float* __restrict__ esrc, float* __restrict__ edst) {
  const int n = blockIdx.x * blockDim.x + threadIdx.x;
  if (n >= N_NODESC) return;
  const float* s = s2 + (size_t)n * NBASEC;
  float a = 0.f, d = 0.f;
#pragma unroll
  for (int b = 0; b < NBASEC; ++b) {
    a += s[b] * cs2[b];
    d += s[b] * cd2[b];
  }
  esrc[n] = a;
  edst[n] = d;
}

// ---------------- CSR scan/scatter ----------------
#define SCAN_NB ((N_NODESC + 255) / 256)   // 196

__global__ void reduce_counts(const int* __restrict__ counts, int* __restrict__ bsums) {
  __shared__ int sm[256];
  const int i = blockIdx.x * 256 + threadIdx.x;
  sm[threadIdx.x] = (i < N_NODESC) ? counts[i] : 0;
  __syncthreads();
  for (int d = 128; d > 0; d >>= 1) {
    if (threadIdx.x < (unsigned)d) sm[threadIdx.x] += sm[threadIdx.x + d];
    __syncthreads();
  }
  if (threadIdx.x == 0) bsums[blockIdx.x] = sm[0];
}

__global__ void scan_bsums_k(int* __restrict__ bsums) {
  __shared__ int sm[256];
  const int v = (threadIdx.x < SCAN_NB) ? bsums[threadIdx.x] : 0;
  sm[threadIdx.x] = v;
  __syncthreads();
  for (int d = 1; d < 256; d <<= 1) {
    const int t = (threadIdx.x >= (unsigned)d) ? sm[threadIdx.x - d] : 0;
    __syncthreads();
    sm[threadIdx.x] += t;
    __syncthreads();
  }
  if (threadIdx.x < SCAN_NB) bsums[threadIdx.x] = sm[threadIdx.x] - v;  // exclusive
}

__global__ void scan_final(const int* __restrict__ counts, const int* __restrict__ bsums,
                           int* __restrict__ offsets) {
  __shared__ int sm[256];
  const int i = blockIdx.x * 256 + threadIdx.x;
  const int v = (i < N_NODESC) ? counts[i] : 0;
  sm[threadIdx.x] = v;
  __syncthreads();
  for (int d = 1; d < 256; d <<= 1) {
    const int t = (threadIdx.x >= (unsigned)d) ? sm[threadIdx.x - d] : 0;
    __syncthreads();
    sm[threadIdx.x] += t;
    __syncthreads();
  }
  if (i < N_NODESC) offsets[i] = bsums[blockIdx.x] + sm[threadIdx.x] - v;
  if (i == 0) offsets[N_NODESC] = N_EDGESC;
}

__global__ void scatter_kernel(const int* __restrict__ dst, const int* __restrict__ src,
                               const int* __restrict__ offsets, int* __restrict__ counts,
                               int* __restrict__ srcs_csr) {
  const int e = blockIdx.x * blockDim.x + threadIdx.x;
  if (e >= N_EDGESC) return;
  const int n = dst[e];
  const int pos = offsets[n] + atomicSub(&counts[n], 1) - 1;
  srcs_csr[pos] = src[e];
}

// ---------- layer-1 softmax-aggregate: 2 edges/wave (32-lane halves), 8 feat/lane --------
__global__ __launch_bounds__(256) void agg1_kernel(
    const unsigned short* __restrict__ h1b, const float* __restrict__ esrc,
    const float* __restrict__ edst, const int* __restrict__ srcs,
    const int* __restrict__ offsets, const float* __restrict__ bias,
    unsigned short* __restrict__ hactb) {
  const int wv = threadIdx.x >> 6;
  const int lane = threadIdx.x & 63;
  const int n = blockIdx.x * 4 + wv;
  if (n >= N_NODESC) return;
  const int half = lane >> 5;      // which edge of the pair
  const int l = lane & 31;         // feature chunk: 8 bf16 at l*8
  const int h = l >> 3;            // head
  const int beg = offsets[n], end = offsets[n + 1];
  const float ed = edst[(unsigned)n * NHEADC + h];

  float wsum = 0.f;
  float acc[8] = {0.f, 0.f, 0.f, 0.f, 0.f, 0.f, 0.f, 0.f};
  int i = beg;
  for (; i + 4 <= end; i += 4) {           // 2 full pairs
    const int sA = srcs[i + half];
    const int sB = srcs[i + 2 + half];
    float tA = esrc[(unsigned)sA * NHEADC + h] + ed;
    float tB = esrc[(unsigned)sB * NHEADC + h] + ed;
    const uint4 hA = *reinterpret_cast<const uint4*>(h1b + ((unsigned)sA << 8) + l * 8);
    const uint4 hB = *reinterpret_cast<const uint4*>(h1b + ((unsigned)sB << 8) + l * 8);
    tA = tA > 0.f ? tA : 0.2f * tA;
    tB = tB > 0.f ? tB : 0.2f * tB;
    const float aA = __expf(tA), aB = __expf(tB);
    wsum += aA + aB;
    acc[0] += aA * blo(hA.x) + aB * blo(hB.x);
    acc[1] += aA * bhi(hA.x) + aB * bhi(hB.x);
    acc[2] += aA * blo(hA.y) + aB * blo(hB.y);
    acc[3] += aA * bhi(hA.y) + aB * bhi(hB.y);
    acc[4] += aA * blo(hA.z) + aB * blo(hB.z);
    acc[5] += aA * bhi(hA.z) + aB * bhi(hB.z);
    acc[6] += aA * blo(hA.w) + aB * blo(hB.w);
    acc[7] += aA * bhi(hA.w) + aB * bhi(hB.w);
  }
  for (; i < end; i += 2) {                // guarded tail pair
    const int e = i + half;
    if (e < end) {
      const int s = srcs[e];
      float t = esrc[(unsigned)s * NHEADC + h] + ed;
      const uint4 hv = *reinterpret_cast<const uint4*>(h1b + ((unsigned)s << 8) + l * 8);
      t = t > 0.f ? t : 0.2f * t;
      const float a = __expf(t);
      wsum += a;
      acc[0] += a * blo(hv.x); acc[1] += a * bhi(hv.x);
      acc[2] += a * blo(hv.y); acc[3] += a * bhi(hv.y);
      acc[4] += a * blo(hv.z); acc[5] += a * bhi(hv.z);
      acc[6] += a * blo(hv.w); acc[7] += a * bhi(hv.w);
    }
  }
  // combine halves
#pragma unroll
  for (int k = 0; k < 8; ++k) acc[k] += __shfl_xor(acc[k], 32);
  wsum += __shfl_xor(wsum, 32);
  if (half == 0) {
    const float inv = 1.f / (wsum + 1e-16f);
    const int f = l * 8;
    const float4 b0 = *reinterpret_cast<const float4*>(bias + f);
    const float4 b1 = *reinterpret_cast<const float4*>(bias + f + 4);
    float v0 = acc[0] * inv + b0.x; v0 = v0 > 0.f ? v0 : __expf(v0) - 1.f;
    float v1 = acc[1] * inv + b0.y; v1 = v1 > 0.f ? v1 : __expf(v1) - 1.f;
    float v2 = acc[2] * inv + b0.z; v2 = v2 > 0.f ? v2 : __expf(v2) - 1.f;
    float v3 = acc[3] * inv + b0.w; v3 = v3 > 0.f ? v3 : __expf(v3) - 1.f;
    float v4 = acc[4] * inv + b1.x; v4 = v4 > 0.f ? v4 : __expf(v4) - 1.f;
    float v5 = acc[5] * inv + b1.y; v5 = v5 > 0.f ? v5 : __expf(v5) - 1.f;
    float v6 = acc[6] * inv + b1.z; v6 = v6 > 0.f ? v6 : __expf(v6) - 1.f;
    float v7 = acc[7] * inv + b1.w; v7 = v7 > 0.f ? v7 : __expf(v7) - 1.f;
    uint4 st;
    st.x = (unsigned)f2bf(v0) | ((unsigned)f2bf(v1) << 16);
    st.y = (unsigned)f2bf(v2) | ((unsigned)f2bf(v3) << 16);
    st.z = (unsigned)f2bf(v4) | ((unsigned)f2bf(v5) << 16);
    st.w = (unsigned)f2bf(v6) | ((unsigned)f2bf(v7) << 16);
    *reinterpret_cast<uint4*>(hactb + ((unsigned)n << 8) + f) = st;
  }
}

// ---------- layer-2 softmax-aggregate: 2 edges/wave, 2 classes/lane (l<20) --------------
__global__ __launch_bounds__(256) void agg2_kernel(
    const unsigned short* __restrict__ g2b, const float* __restrict__ esrc,
    const float* __restrict__ edst, const int* __restrict__ srcs,
    const int* __restrict__ offsets, float* __restrict__ out) {
  const int wv = threadIdx.x >> 6;
  const int lane = threadIdx.x & 63;
  const int n = blockIdx.x * 4 + wv;
  if (n >= N_NODESC) return;
  const int half = lane >> 5;
  const int l = lane & 31;
  const bool act = l < (NCLASSC / 2);
  const int beg = offsets[n], end = offsets[n + 1];
  const float ed = edst[n];

  float wsum = 0.f, acc0 = 0.f, acc1 = 0.f;
  int i = beg;
  for (; i + 4 <= end; i += 4) {
    const int sA = srcs[i + half];
    const int sB = srcs[i + 2 + half];
    float tA = esrc[sA] + ed;
    float tB = esrc[sB] + ed;
    unsigned int gA = 0, gB = 0;
    if (act) {
      gA = *reinterpret_cast<const unsigned int*>(g2b + (unsigned)sA * NCLASSC + l * 2);
      gB = *reinterpret_cast<const unsigned int*>(g2b + (unsigned)sB * NCLASSC + l * 2);
    }
    tA = tA > 0.f ? tA : 0.2f * tA;
    tB = tB > 0.f ? tB : 0.2f * tB;
    const float aA = __expf(tA), aB = __expf(tB);
    wsum += aA + aB;
    acc0 += aA * blo(gA) + aB * blo(gB);
    acc1 += aA * bhi(gA) + aB * bhi(gB);
  }
  for (; i < end; i += 2) {
    const int e = i + half;
    if (e < end) {
      const int s = srcs[e];
      float t = esrc[s] + ed;
      unsigned int g = 0;
      if (act) g = *reinterpret_cast<const unsigned int*>(g2b + (unsigned)s * NCLASSC + l * 2);
      t = t > 0.f ? t : 0.2f * t;
      const float a = __expf(t);
      wsum += a;
      acc0 += a * blo(g);
      acc1 += a * bhi(g);
    }
  }
  acc0 += __shfl_xor(acc0, 32);
  acc1 += __shfl_xor(acc1, 32);
  wsum += __shfl_xor(wsum, 32);
  if (half == 0 && act) {
    const float inv = 1.f / (wsum + 1e-16f);
    float2 o;
    o.x = acc0 * inv;
    o.y = acc1 * inv;
    *reinterpret_cast<float2*>(out + (size_t)n * NCLASSC + l * 2) = o;
  }
}

extern "C" void kernel_launch(void* const* d_in, const int* in_sizes, int n_in,
                              void* d_out, int out_size, void* d_ws, size_t ws_size,
                              hipStream_t stream) {
  const float* x   = (const float*)d_in[0];
  const int*   ei  = (const int*)d_in[1];
  const float* W1  = (const float*)d_in[2];
  const float* b1  = (const float*)d_in[3];
  const float* B1  = (const float*)d_in[4];
  const float* cs1 = (const float*)d_in[5];
  const float* cd1 = (const float*)d_in[6];
  const float* W2  = (const float*)d_in[7];
  const float* B2  = (const float*)d_in[8];
  const float* cs2 = (const float*)d_in[9];
  const float* cd2 = (const float*)d_in[10];
  const int* srcA = ei;
  const int* dstA = ei + N_EDGESC;
  float* out = (float*)d_out;

  char* ws = (char*)d_ws;
  size_t off = 0;
  auto alloc = [&](size_t bytes) -> void* {
    void* p = ws + off;
    off += (bytes + 255) & ~(size_t)255;
    return p;
  };
  unsigned short* xb    = (unsigned short*)alloc((size_t)N_NODESC * NFEATC * 2);
  unsigned short* h1b   = (unsigned short*)alloc((size_t)N_NODESC * HD1C * 2);
  unsigned short* hactb = (unsigned short*)alloc((size_t)N_NODESC * HD1C * 2);
  unsigned short* g2b   = (unsigned short*)alloc((size_t)N_NODESC * NCLASSC * 2);
  unsigned short* W1T   = (unsigned short*)alloc((size_t)W1TROWS * NFEATC * 2);
  unsigned short* W2T   = (unsigned short*)alloc((size_t)W2TROWS * HD1C * 2);
  float* s1     = (float*)alloc((size_t)N_NODESC * NBASEC * 4);
  float* s2     = (float*)alloc((size_t)N_NODESC * NBASEC * 4);
  float* esrc1  = (float*)alloc((size_t)N_NODESC * NHEADC * 4);
  float* edst1  = (float*)alloc((size_t)N_NODESC * NHEADC * 4);
  float* esrc2  = (float*)alloc((size_t)N_NODESC * 4);
  float* edst2  = (float*)alloc((size_t)N_NODESC * 4);
  int* counts   = (int*)alloc((size_t)N_NODESC * 4);
  int* offsets  = (int*)alloc((size_t)(N_NODESC + 1) * 4);
  int* bsums    = (int*)alloc((size_t)SCAN_NB * 4);
  int* srcs_csr = (int*)alloc((size_t)N_EDGESC * 4);

  hipMemsetAsync(counts, 0, (size_t)N_NODESC * 4, stream);

  // fused prep (x->bf16, W1T, W2T, dst histogram)
  prep_kernel<<<PREP_NB, 256, 0, stream>>>(x, xb, W1, B1, W1T, W2, B2, W2T, dstA, counts);

  // CSR scan + scatter
  reduce_counts<<<SCAN_NB, 256, 0, stream>>>(counts, bsums);
  scan_bsums_k<<<1, 256, 0, stream>>>(bsums);
  scan_final<<<SCAN_NB, 256, 0, stream>>>(counts, bsums, offsets);
  scatter_kernel<<<(N_EDGESC + 255) / 256, 256, 0, stream>>>(dstA, srcA, offsets, counts,
                                                             srcs_csr);

  // layer 1: [h1b | s1] = x @ [W1 | B1]  (MFMA)
  dim3 gg1((N_NODESC + 255) / 256, W1TROWS / 64);
  mfma_gemm_bt<<<gg1, 256, 0, stream>>>(xb, W1T, N_NODESC, NFEATC, HD1C + NBASEC, HD1C,
                                        h1b, s1);
  attn_scalars1<<<(N_NODESC + 255) / 256, 256, 0, stream>>>(s1, cs1, cd1, esrc1, edst1);
  agg1_kernel<<<(N_NODESC + 3) / 4, 256, 0, stream>>>(h1b, esrc1, edst1, srcs_csr, offsets,
                                                      b1, hactb);

  // layer 2: [g2b | s2] = hact @ [W2 | B2]  (MFMA)
  dim3 gg2((N_NODESC + 255) / 256, W2TROWS / 64);
  mfma_gemm_bt<<<gg2, 256, 0, stream>>>(hactb, W2T, N_NODESC, HD1C, NCLASSC + NBASEC,
                                        NCLASSC, g2b, s2);
  attn_scalars2<<<(N_NODESC + 255) / 256, 256, 0, stream>>>(s2, cs2, cd2, esrc2, edst2);
  agg2_kernel<<<(N_NODESC + 3) / 4, 256, 0, stream>>>(g2b, esrc2, edst2, srcs_csr, offsets,
                                                      out);
}

// Round 7
// 298.049 us; speedup vs baseline: 1.5659x; 1.0611x over previous
//
#include <hip/hip_runtime.h>

#define N_NODESC 50000
#define N_EDGESC 800000
#define NFEATC 128
#define NHIDC 64
#define NHEADC 4
#define NBASEC 8
#define NCLASSC 40
#define HD1C (NHEADC * NHIDC)        // 256
#define W1TROWS 320                  // 256 + 8, padded to 64-multiple
#define W2TROWS 64                   // 40 + 8, padded

typedef __attribute__((ext_vector_type(8))) short bf16x8;
typedef __attribute__((ext_vector_type(4))) float f32x4;

__device__ inline float bf2f(unsigned short u) {
  union { unsigned int i; float f; } v;
  v.i = ((unsigned int)u) << 16;
  return v.f;
}
__device__ inline float blo(unsigned int u) {
  union { unsigned int i; float f; } v; v.i = u << 16; return v.f;
}
__device__ inline float bhi(unsigned int u) {
  union { unsigned int i; float f; } v; v.i = u & 0xffff0000u; return v.f;
}
__device__ inline unsigned short f2bf(float x) {
  union { float f; unsigned int i; } v;
  v.f = x;
  unsigned int r = v.i + 0x7FFF + ((v.i >> 16) & 1);  // RNE
  return (unsigned short)(r >> 16);
}

// ======== layer-1 fused: [h1 | s1] = x @ [W1|B1] (MFMA, x staged in LDS once),
//          esrc1/edst1 computed in-epilogue from the s-columns ========
__global__ __launch_bounds__(256) void gemm1_fused(
    const float* __restrict__ x, const unsigned short* __restrict__ W1T,
    const float* __restrict__ cs1, const float* __restrict__ cd1,
    unsigned short* __restrict__ h1b, float* __restrict__ esrc, float* __restrict__ edst) {
  __shared__ unsigned short As[256 * 132];   // 256 rows, stride 132 bf16 (264 B, pad kills conflicts)
  __shared__ float sS[256 * 8];              // s-columns staging for epilogue
  const int tid = threadIdx.x;
  const int wave = tid >> 6, lane = tid & 63;
  const int row0 = blockIdx.x * 256;

  // ---- stage x (fp32 -> bf16) into LDS, coalesced float4 ----
#pragma unroll
  for (int p = 0; p < 32; ++p) {
    const int g4 = p * 256 + tid;            // 8192 float4 = 256 rows x 32
    const int r = g4 >> 5;
    const int k4 = g4 & 31;
    int grow = row0 + r;
    grow = grow < N_NODESC ? grow : N_NODESC - 1;
    const float4 v = *reinterpret_cast<const float4*>(x + (size_t)grow * NFEATC + k4 * 4);
    ushort4 o;
    o.x = f2bf(v.x); o.y = f2bf(v.y); o.z = f2bf(v.z); o.w = f2bf(v.w);
    *reinterpret_cast<ushort4*>(&As[r * 132 + k4 * 4]) = o;
  }
  __syncthreads();

  const int lm = lane & 15, q = lane >> 4, kq = q * 8;
  // ---- 5 col-tiles of 64 (tiles 0..3 = h1 cols 0..255; tile 4 = s cols 256..263 + pad) ----
  for (int t = 0; t < 5; ++t) {
    const int n0 = t * 64;
    f32x4 acc[4][4] = {};
#pragma unroll
    for (int k0 = 0; k0 < NFEATC; k0 += 32) {
      bf16x8 af[4], bfr[4];
#pragma unroll
      for (int mi = 0; mi < 4; ++mi)
        af[mi] = *reinterpret_cast<const bf16x8*>(&As[(wave * 64 + mi * 16 + lm) * 132 + k0 + kq]);
#pragma unroll
      for (int ni = 0; ni < 4; ++ni)
        bfr[ni] = *reinterpret_cast<const bf16x8*>(W1T + (size_t)(n0 + ni * 16 + lm) * NFEATC + k0 + kq);
#pragma unroll
      for (int mi = 0; mi < 4; ++mi)
#pragma unroll
        for (int ni = 0; ni < 4; ++ni)
          acc[mi][ni] = __builtin_amdgcn_mfma_f32_16x16x32_bf16(af[mi], bfr[ni], acc[mi][ni],
                                                                0, 0, 0);
    }
    if (t < 4) {
#pragma unroll
      for (int mi = 0; mi < 4; ++mi)
#pragma unroll
        for (int r = 0; r < 4; ++r) {
          const int row = row0 + wave * 64 + mi * 16 + q * 4 + r;
          if (row >= N_NODESC) continue;
#pragma unroll
          for (int ni = 0; ni < 4; ++ni)
            h1b[(size_t)row * HD1C + n0 + ni * 16 + lm] = f2bf(acc[mi][ni][r]);
        }
    } else {
      // s-columns: ni==0, lm<8 -> cols 256..263. Stage wave-local rows to LDS.
      if (lm < 8) {
#pragma unroll
        for (int mi = 0; mi < 4; ++mi)
#pragma unroll
          for (int r = 0; r < 4; ++r)
            sS[(wave * 64 + mi * 16 + q * 4 + r) * 8 + lm] = acc[mi][0][r];
      }
      // wave-local write->read (in-order DS pipe); each lane handles one of its wave's rows
      const int rloc = wave * 64 + lane;
      const int grow = row0 + rloc;
      if (grow < N_NODESC) {
        float sb[8];
#pragma unroll
        for (int b = 0; b < 8; ++b) sb[b] = sS[rloc * 8 + b];
#pragma unroll
        for (int h = 0; h < NHEADC; ++h) {
          float a = 0.f, d = 0.f;
#pragma unroll
          for (int b = 0; b < NBASEC; ++b) {
            a += sb[b] * cs1[b * NHEADC + h];
            d += sb[b] * cd1[b * NHEADC + h];
          }
          esrc[grow * NHEADC + h] = a;
          edst[grow * NHEADC + h] = d;
        }
      }
    }
  }
}

// ======== layer-2 fused: [g2 | s2] = hact @ [W2|B2] (MFMA, direct-global A),
//          esrc2/edst2 in-epilogue ========
__global__ __launch_bounds__(256) void gemm2_fused(
    const unsigned short* __restrict__ A, const unsigned short* __restrict__ W2T,
    const float* __restrict__ cs2, const float* __restrict__ cd2,
    unsigned short* __restrict__ g2b, float* __restrict__ esrc, float* __restrict__ edst) {
  __shared__ float sS[256 * 8];
  const int wave = threadIdx.x >> 6;
  const int lane = threadIdx.x & 63;
  const int m0 = blockIdx.x * 256 + wave * 64;
  const int lm = lane & 15, q = lane >> 4, kq = q * 8;
  f32x4 acc[4][4] = {};

  for (int k0 = 0; k0 < HD1C; k0 += 32) {
    bf16x8 af[4], bfr[4];
#pragma unroll
    for (int mi = 0; mi < 4; ++mi) {
      int row = m0 + mi * 16 + lm;
      row = row < N_NODESC ? row : N_NODESC - 1;
      af[mi] = *reinterpret_cast<const bf16x8*>(A + (size_t)row * HD1C + k0 + kq);
    }
#pragma unroll
    for (int ni = 0; ni < 4; ++ni)
      bfr[ni] = *reinterpret_cast<const bf16x8*>(W2T + (size_t)(ni * 16 + lm) * HD1C + k0 + kq);
#pragma unroll
    for (int mi = 0; mi < 4; ++mi)
#pragma unroll
      for (int ni = 0; ni < 4; ++ni)
        acc[mi][ni] = __builtin_amdgcn_mfma_f32_16x16x32_bf16(af[mi], bfr[ni], acc[mi][ni],
                                                              0, 0, 0);
  }
  // g2 cols 0..39
#pragma unroll
  for (int mi = 0; mi < 4; ++mi)
#pragma unroll
    for (int r = 0; r < 4; ++r) {
      const int row = m0 + mi * 16 + q * 4 + r;
      if (row >= N_NODESC) continue;
#pragma unroll
      for (int ni = 0; ni < 3; ++ni) {
        const int col = ni * 16 + lm;
        if (col < NCLASSC) g2b[(size_t)row * NCLASSC + col] = f2bf(acc[mi][ni][r]);
      }
    }
  // s-cols 40..47: ni==2, lm in [8,16)
  if (lm >= 8) {
#pragma unroll
    for (int mi = 0; mi < 4; ++mi)
#pragma unroll
      for (int r = 0; r < 4; ++r)
        sS[(wave * 64 + mi * 16 + q * 4 + r) * 8 + (lm - 8)] = acc[mi][2][r];
  }
  const int rloc = wave * 64 + lane;
  const int grow = blockIdx.x * 256 + rloc;
  if (grow < N_NODESC) {
    float sb[8];
#pragma unroll
    for (int b = 0; b < 8; ++b) sb[b] = sS[rloc * 8 + b];
    float a = 0.f, d = 0.f;
#pragma unroll
    for (int b = 0; b < NBASEC; ++b) {
      a += sb[b] * cs2[b];
      d += sb[b] * cd2[b];
    }
    esrc[grow] = a;
    edst[grow] = d;
  }
}

// ---------------- fused prep: W1T | W2T | dst histogram ----------------
#define W1T_NB ((W1TROWS * NFEATC + 255) / 256)                 // 160
#define W2T_NB ((W2TROWS * HD1C + 255) / 256)                   // 64
#define HIST_NB ((N_EDGESC + 255) / 256)                        // 3125
#define PREP_NB (W1T_NB + W2T_NB + HIST_NB)

__global__ __launch_bounds__(256) void prep_kernel(
    const float* __restrict__ W1, const float* __restrict__ B1,
    unsigned short* __restrict__ W1T,
    const float* __restrict__ W2, const float* __restrict__ B2,
    unsigned short* __restrict__ W2T,
    const int* __restrict__ dst, int* __restrict__ counts) {
  int b = blockIdx.x;
  if (b < W1T_NB) {
    const int i = b * 256 + threadIdx.x;
    if (i < W1TROWS * NFEATC) {
      const int n = i / NFEATC, k = i - n * NFEATC;
      float v = 0.f;
      if (n < HD1C) v = W1[(size_t)k * HD1C + n];
      else if (n < HD1C + NBASEC) v = B1[(size_t)k * NBASEC + (n - HD1C)];
      W1T[i] = f2bf(v);
    }
    return;
  }
  b -= W1T_NB;
  if (b < W2T_NB) {
    const int i = b * 256 + threadIdx.x;
    if (i < W2TROWS * HD1C) {
      const int n = i / HD1C, k = i - n * HD1C;
      float v = 0.f;
      if (n < NCLASSC) v = W2[(size_t)k * NCLASSC + n];
      else if (n < NCLASSC + NBASEC) v = B2[(size_t)k * NBASEC + (n - NCLASSC)];
      W2T[i] = f2bf(v);
    }
    return;
  }
  b -= W2T_NB;
  {
    const int e = b * 256 + threadIdx.x;
    if (e < N_EDGESC) atomicAdd(&counts[dst[e]], 1);
  }
}

// ---------------- CSR scan/scatter ----------------
#define SCAN_NB ((N_NODESC + 255) / 256)   // 196

__global__ void reduce_counts(const int* __restrict__ counts, int* __restrict__ bsums) {
  __shared__ int sm[256];
  const int i = blockIdx.x * 256 + threadIdx.x;
  sm[threadIdx.x] = (i < N_NODESC) ? counts[i] : 0;
  __syncthreads();
  for (int d = 128; d > 0; d >>= 1) {
    if (threadIdx.x < (unsigned)d) sm[threadIdx.x] += sm[threadIdx.x + d];
    __syncthreads();
  }
  if (threadIdx.x == 0) bsums[blockIdx.x] = sm[0];
}

__global__ void scan_bsums_k(int* __restrict__ bsums) {
  __shared__ int sm[256];
  const int v = (threadIdx.x < SCAN_NB) ? bsums[threadIdx.x] : 0;
  sm[threadIdx.x] = v;
  __syncthreads();
  for (int d = 1; d < 256; d <<= 1) {
    const int t = (threadIdx.x >= (unsigned)d) ? sm[threadIdx.x - d] : 0;
    __syncthreads();
    sm[threadIdx.x] += t;
    __syncthreads();
  }
  if (threadIdx.x < SCAN_NB) bsums[threadIdx.x] = sm[threadIdx.x] - v;  // exclusive
}

__global__ void scan_final(const int* __restrict__ counts, const int* __restrict__ bsums,
                           int* __restrict__ offsets) {
  __shared__ int sm[256];
  const int i = blockIdx.x * 256 + threadIdx.x;
  const int v = (i < N_NODESC) ? counts[i] : 0;
  sm[threadIdx.x] = v;
  __syncthreads();
  for (int d = 1; d < 256; d <<= 1) {
    const int t = (threadIdx.x >= (unsigned)d) ? sm[threadIdx.x - d] : 0;
    __syncthreads();
    sm[threadIdx.x] += t;
    __syncthreads();
  }
  if (i < N_NODESC) offsets[i] = bsums[blockIdx.x] + sm[threadIdx.x] - v;
  if (i == 0) offsets[N_NODESC] = N_EDGESC;
}

__global__ void scatter_kernel(const int* __restrict__ dst, const int* __restrict__ src,
                               const int* __restrict__ offsets, int* __restrict__ counts,
                               int* __restrict__ srcs_csr) {
  const int e = blockIdx.x * blockDim.x + threadIdx.x;
  if (e >= N_EDGESC) return;
  const int n = dst[e];
  const int pos = offsets[n] + atomicSub(&counts[n], 1) - 1;
  srcs_csr[pos] = src[e];
}

// ---------- layer-1 softmax-aggregate: 2 edges/wave (32-lane halves), 8 feat/lane --------
__global__ __launch_bounds__(256) void agg1_kernel(
    const unsigned short* __restrict__ h1b, const float* __restrict__ esrc,
    const float* __restrict__ edst, const int* __restrict__ srcs,
    const int* __restrict__ offsets, const float* __restrict__ bias,
    unsigned short* __restrict__ hactb) {
  const int wv = threadIdx.x >> 6;
  const int lane = threadIdx.x & 63;
  const int n = blockIdx.x * 4 + wv;
  if (n >= N_NODESC) return;
  const int half = lane >> 5;
  const int l = lane & 31;
  const int h = l >> 3;
  const int beg = offsets[n], end = offsets[n + 1];
  const float ed = edst[(unsigned)n * NHEADC + h];

  float wsum = 0.f;
  float acc[8] = {0.f, 0.f, 0.f, 0.f, 0.f, 0.f, 0.f, 0.f};
  int i = beg;
  for (; i + 4 <= end; i += 4) {
    const int sA = srcs[i + half];
    const int sB = srcs[i + 2 + half];
    float tA = esrc[(unsigned)sA * NHEADC + h] + ed;
    float tB = esrc[(unsigned)sB * NHEADC + h] + ed;
    const uint4 hA = *reinterpret_cast<const uint4*>(h1b + ((unsigned)sA << 8) + l * 8);
    const uint4 hB = *reinterpret_cast<const uint4*>(h1b + ((unsigned)sB << 8) + l * 8);
    tA = tA > 0.f ? tA : 0.2f * tA;
    tB = tB > 0.f ? tB : 0.2f * tB;
    const float aA = __expf(tA), aB = __expf(tB);
    wsum += aA + aB;
    acc[0] += aA * blo(hA.x) + aB * blo(hB.x);
    acc[1] += aA * bhi(hA.x) + aB * bhi(hB.x);
    acc[2] += aA * blo(hA.y) + aB * blo(hB.y);
    acc[3] += aA * bhi(hA.y) + aB * bhi(hB.y);
    acc[4] += aA * blo(hA.z) + aB * blo(hB.z);
    acc[5] += aA * bhi(hA.z) + aB * bhi(hB.z);
    acc[6] += aA * blo(hA.w) + aB * blo(hB.w);
    acc[7] += aA * bhi(hA.w) + aB * bhi(hB.w);
  }
  for (; i < end; i += 2) {
    const int e = i + half;
    if (e < end) {
      const int s = srcs[e];
      float t = esrc[(unsigned)s * NHEADC + h] + ed;
      const uint4 hv = *reinterpret_cast<const uint4*>(h1b + ((unsigned)s << 8) + l * 8);
      t = t > 0.f ? t : 0.2f * t;
      const float a = __expf(t);
      wsum += a;
      acc[0] += a * blo(hv.x); acc[1] += a * bhi(hv.x);
      acc[2] += a * blo(hv.y); acc[3] += a * bhi(hv.y);
      acc[4] += a * blo(hv.z); acc[5] += a * bhi(hv.z);
      acc[6] += a * blo(hv.w); acc[7] += a * bhi(hv.w);
    }
  }
#pragma unroll
  for (int k = 0; k < 8; ++k) acc[k] += __shfl_xor(acc[k], 32);
  wsum += __shfl_xor(wsum, 32);
  if (half == 0) {
    const float inv = 1.f / (wsum + 1e-16f);
    const int f = l * 8;
    const float4 b0 = *reinterpret_cast<const float4*>(bias + f);
    const float4 b1 = *reinterpret_cast<const float4*>(bias + f + 4);
    float v0 = acc[0] * inv + b0.x; v0 = v0 > 0.f ? v0 : __expf(v0) - 1.f;
    float v1 = acc[1] * inv + b0.y; v1 = v1 > 0.f ? v1 : __expf(v1) - 1.f;
    float v2 = acc[2] * inv + b0.z; v2 = v2 > 0.f ? v2 : __expf(v2) - 1.f;
    float v3 = acc[3] * inv + b0.w; v3 = v3 > 0.f ? v3 : __expf(v3) - 1.f;
    float v4 = acc[4] * inv + b1.x; v4 = v4 > 0.f ? v4 : __expf(v4) - 1.f;
    float v5 = acc[5] * inv + b1.y; v5 = v5 > 0.f ? v5 : __expf(v5) - 1.f;
    float v6 = acc[6] * inv + b1.z; v6 = v6 > 0.f ? v6 : __expf(v6) - 1.f;
    float v7 = acc[7] * inv + b1.w; v7 = v7 > 0.f ? v7 : __expf(v7) - 1.f;
    uint4 st;
    st.x = (unsigned)f2bf(v0) | ((unsigned)f2bf(v1) << 16);
    st.y = (unsigned)f2bf(v2) | ((unsigned)f2bf(v3) << 16);
    st.z = (unsigned)f2bf(v4) | ((unsigned)f2bf(v5) << 16);
    st.w = (unsigned)f2bf(v6) | ((unsigned)f2bf(v7) << 16);
    *reinterpret_cast<uint4*>(hactb + ((unsigned)n << 8) + f) = st;
  }
}

// ---------- layer-2 softmax-aggregate: 2 edges/wave, 2 classes/lane (l<20) --------------
__global__ __launch_bounds__(256) void agg2_kernel(
    const unsigned short* __restrict__ g2b, const float* __restrict__ esrc,
    const float* __restrict__ edst, const int* __restrict__ srcs,
    const int* __restrict__ offsets, float* __restrict__ out) {
  const int wv = threadIdx.x >> 6;
  const int lane = threadIdx.x & 63;
  const int n = blockIdx.x * 4 + wv;
  if (n >= N_NODESC) return;
  const int half = lane >> 5;
  const int l = lane & 31;
  const bool act = l < (NCLASSC / 2);
  const int beg = offsets[n], end = offsets[n + 1];
  const float ed = edst[n];

  float wsum = 0.f, acc0 = 0.f, acc1 = 0.f;
  int i = beg;
  for (; i + 4 <= end; i += 4) {
    const int sA = srcs[i + half];
    const int sB = srcs[i + 2 + half];
    float tA = esrc[sA] + ed;
    float tB = esrc[sB] + ed;
    unsigned int gA = 0, gB = 0;
    if (act) {
      gA = *reinterpret_cast<const unsigned int*>(g2b + (unsigned)sA * NCLASSC + l * 2);
      gB = *reinterpret_cast<const unsigned int*>(g2b + (unsigned)sB * NCLASSC + l * 2);
    }
    tA = tA > 0.f ? tA : 0.2f * tA;
    tB = tB > 0.f ? tB : 0.2f * tB;
    const float aA = __expf(tA), aB = __expf(tB);
    wsum += aA + aB;
    acc0 += aA * blo(gA) + aB * blo(gB);
    acc1 += aA * bhi(gA) + aB * bhi(gB);
  }
  for (; i < end; i += 2) {
    const int e = i + half;
    if (e < end) {
      const int s = srcs[e];
      float t = esrc[s] + ed;
      unsigned int g = 0;
      if (act) g = *reinterpret_cast<const unsigned int*>(g2b + (unsigned)s * NCLASSC + l * 2);
      t = t > 0.f ? t : 0.2f * t;
      const float a = __expf(t);
      wsum += a;
      acc0 += a * blo(g);
      acc1 += a * bhi(g);
    }
  }
  acc0 += __shfl_xor(acc0, 32);
  acc1 += __shfl_xor(acc1, 32);
  wsum += __shfl_xor(wsum, 32);
  if (half == 0 && act) {
    const float inv = 1.f / (wsum + 1e-16f);
    float2 o;
    o.x = acc0 * inv;
    o.y = acc1 * inv;
    *reinterpret_cast<float2*>(out + (size_t)n * NCLASSC + l * 2) = o;
  }
}

extern "C" void kernel_launch(void* const* d_in, const int* in_sizes, int n_in,
                              void* d_out, int out_size, void* d_ws, size_t ws_size,
                              hipStream_t stream) {
  const float* x   = (const float*)d_in[0];
  const int*   ei  = (const int*)d_in[1];
  const float* W1  = (const float*)d_in[2];
  const float* b1  = (const float*)d_in[3];
  const float* B1  = (const float*)d_in[4];
  const float* cs1 = (const float*)d_in[5];
  const float* cd1 = (const float*)d_in[6];
  const float* W2  = (const float*)d_in[7];
  const float* B2  = (const float*)d_in[8];
  const float* cs2 = (const float*)d_in[9];
  const float* cd2 = (const float*)d_in[10];
  const int* srcA = ei;
  const int* dstA = ei + N_EDGESC;
  float* out = (float*)d_out;

  char* ws = (char*)d_ws;
  size_t off = 0;
  auto alloc = [&](size_t bytes) -> void* {
    void* p = ws + off;
    off += (bytes + 255) & ~(size_t)255;
    return p;
  };
  unsigned short* h1b   = (unsigned short*)alloc((size_t)N_NODESC * HD1C * 2);
  unsigned short* hactb = (unsigned short*)alloc((size_t)N_NODESC * HD1C * 2);
  unsigned short* g2b   = (unsigned short*)alloc((size_t)N_NODESC * NCLASSC * 2);
  unsigned short* W1T   = (unsigned short*)alloc((size_t)W1TROWS * NFEATC * 2);
  unsigned short* W2T   = (unsigned short*)alloc((size_t)W2TROWS * HD1C * 2);
  float* esrc1  = (float*)alloc((size_t)N_NODESC * NHEADC * 4);
  float* edst1  = (float*)alloc((size_t)N_NODESC * NHEADC * 4);
  float* esrc2  = (float*)alloc((size_t)N_NODESC * 4);
  float* edst2  = (float*)alloc((size_t)N_NODESC * 4);
  int* counts   = (int*)alloc((size_t)N_NODESC * 4);
  int* offsets  = (int*)alloc((size_t)(N_NODESC + 1) * 4);
  int* bsums    = (int*)alloc((size_t)SCAN_NB * 4);
  int* srcs_csr = (int*)alloc((size_t)N_EDGESC * 4);

  hipMemsetAsync(counts, 0, (size_t)N_NODESC * 4, stream);

  // prep (W1T, W2T, dst histogram)
  prep_kernel<<<PREP_NB, 256, 0, stream>>>(W1, B1, W1T, W2, B2, W2T, dstA, counts);

  // CSR scan + scatter
  reduce_counts<<<SCAN_NB, 256, 0, stream>>>(counts, bsums);
  scan_bsums_k<<<1, 256, 0, stream>>>(bsums);
  scan_final<<<SCAN_NB, 256, 0, stream>>>(counts, bsums, offsets);
  scatter_kernel<<<(N_EDGESC + 255) / 256, 256, 0, stream>>>(dstA, srcA, offsets, counts,
                                                             srcs_csr);

  // layer 1 (GEMM + attn scalars fused)
  gemm1_fused<<<(N_NODESC + 255) / 256, 256, 0, stream>>>(x, W1T, cs1, cd1, h1b, esrc1,
                                                          edst1);
  agg1_kernel<<<(N_NODESC + 3) / 4, 256, 0, stream>>>(h1b, esrc1, edst1, srcs_csr, offsets,
                                                      b1, hactb);

  // layer 2 (GEMM + attn scalars fused)
  gemm2_fused<<<(N_NODESC + 255) / 256, 256, 0, stream>>>(hactb, W2T, cs2, cd2, g2b, esrc2,
                                                          edst2);
  agg2_kernel<<<(N_NODESC + 3) / 4, 256, 0, stream>>>(g2b, esrc2, edst2, srcs_csr, offsets,
                                                      out);
}